// Round 2
// baseline (4359.852 us; speedup 1.0000x reference)
//
#include <hip/hip_runtime.h>
#include <cstdint>
#include <cstddef>

typedef unsigned int u32;

#define NT 100000
#define NC 25000
#define ETT 800000
#define ECT 400000
#define SLOPE 0.2f

// out[N,128] = act(in[N,K] @ W[K,128] + bias). All fp32.
// Block=256: 32 rows x 128 cols per block; thread t -> row rl=t>>3, col groups
// (t&7)*4 + {0,32,64,96}.
template<int K>
__global__ __launch_bounds__(256) void gemm_kernel(const float* __restrict__ in,
    const float* __restrict__ W, const float* __restrict__ bias,
    float* __restrict__ out, int N, int relu)
{
  __shared__ float s_in[32][33];
  __shared__ float s_W[32][128];
  const int t = threadIdx.x;
  const int row0 = blockIdx.x * 32;
  const int rl = t >> 3;
  const int cg = t & 7;
  float acc[4][4];
  for (int g = 0; g < 4; ++g)
    for (int j = 0; j < 4; ++j)
      acc[g][j] = bias ? bias[g * 32 + cg * 4 + j] : 0.f;

  for (int kc = 0; kc < K; kc += 32) {
    // stage input tile (32 rows x 32 k)
    {
      const int gr = row0 + rl;
      float4 f = make_float4(0.f, 0.f, 0.f, 0.f);
      if (gr < N)
        f = *(const float4*)(in + (size_t)gr * K + kc + cg * 4);
      s_in[rl][cg * 4 + 0] = f.x; s_in[rl][cg * 4 + 1] = f.y;
      s_in[rl][cg * 4 + 2] = f.z; s_in[rl][cg * 4 + 3] = f.w;
    }
    // stage W chunk (32 k x 128 cols)
    for (int j = 0; j < 4; ++j) {
      const int idx = t + j * 256;
      const int k = idx >> 5;
      const int c4 = (idx & 31) * 4;
      *(float4*)&s_W[k][c4] = *(const float4*)(W + (size_t)(kc + k) * 128 + c4);
    }
    __syncthreads();
#pragma unroll 8
    for (int k = 0; k < 32; ++k) {
      const float a = s_in[rl][k];
      for (int g = 0; g < 4; ++g) {
        const float4 w = *(const float4*)&s_W[k][g * 32 + cg * 4];
        acc[g][0] = fmaf(a, w.x, acc[g][0]);
        acc[g][1] = fmaf(a, w.y, acc[g][1]);
        acc[g][2] = fmaf(a, w.z, acc[g][2]);
        acc[g][3] = fmaf(a, w.w, acc[g][3]);
      }
    }
    __syncthreads();
  }
  const int gr = row0 + rl;
  if (gr < N) {
    for (int g = 0; g < 4; ++g) {
      float x0 = acc[g][0], x1 = acc[g][1], x2 = acc[g][2], x3 = acc[g][3];
      if (relu) { x0 = fmaxf(x0, 0.f); x1 = fmaxf(x1, 0.f); x2 = fmaxf(x2, 0.f); x3 = fmaxf(x3, 0.f); }
      *(float4*)(out + (size_t)gr * 128 + g * 32 + cg * 4) = make_float4(x0, x1, x2, x3);
    }
  }
}

// fold[k][h] = sum_c W[k, h*32+c] * att[h, c]   (128x4 effective attention matrix)
__global__ void fold_kernel(const float* __restrict__ W, const float* __restrict__ att,
                            float* __restrict__ fold)
{
  const int k = threadIdx.x;  // 128 threads
  for (int h = 0; h < 4; ++h) {
    float s = 0.f;
    for (int c = 0; c < 32; ++c)
      s = fmaf(W[k * 128 + h * 32 + c], att[h * 32 + c], s);
    fold[k * 4 + h] = s;
  }
}

// cbias[j] = 0.25*bsd[j] + 0.25*bds[j] + 0.5*bct[j]
__global__ void cbias_kernel(const float* __restrict__ bsd, const float* __restrict__ bds,
                             const float* __restrict__ bct, float* __restrict__ cbias)
{
  const int j = threadIdx.x;  // 128
  cbias[j] = 0.25f * bsd[j] + 0.25f * bds[j] + 0.5f * bct[j];
}

// a[n,h] = sum_k h[n,k] * fold[k,h]  (two folds per pass; null out -> skipped)
__global__ __launch_bounds__(128) void node_att_kernel(const float* __restrict__ h,
    const float* __restrict__ fold_s, const float* __restrict__ fold_d,
    float* __restrict__ a_s, float* __restrict__ a_d, int N)
{
  __shared__ float s_h[32][129];
  __shared__ float s_fs[512];
  __shared__ float s_fd[512];
  const int t = threadIdx.x;
  const int n0 = blockIdx.x * 32;
  for (int i = t; i < 512; i += 128) {
    s_fs[i] = fold_s ? fold_s[i] : 0.f;
    s_fd[i] = fold_d ? fold_d[i] : 0.f;
  }
  for (int r = 0; r < 32; ++r) {
    const int n = n0 + r;
    s_h[r][t] = (n < N) ? h[(size_t)n * 128 + t] : 0.f;
  }
  __syncthreads();
  const int nl = t >> 2, hh = t & 3;
  float ss = 0.f, sd = 0.f;
#pragma unroll 16
  for (int k = 0; k < 128; ++k) {
    const float v = s_h[nl][k];
    ss = fmaf(v, s_fs[k * 4 + hh], ss);
    sd = fmaf(v, s_fd[k * 4 + hh], sd);
  }
  const int n = n0 + nl;
  if (n < N) {
    if (a_s) a_s[n * 4 + hh] = ss;
    if (a_d) a_d[n * 4 + hh] = sd;
  }
}

// Pass 1: den[d,h] += exp(leakyrelu(a_s[s,h]+a_d[d,h])). One thread per (edge,head).
// e >= n_edges are self-loops (s=d=e-n_edges).
__global__ void den_kernel(const int* __restrict__ src, const int* __restrict__ dst,
    int n_edges, int n_loops, const float* __restrict__ a_s, const float* __restrict__ a_d,
    float* __restrict__ den)
{
  const int tid = blockIdx.x * blockDim.x + threadIdx.x;
  const int e = tid >> 2;
  if (e >= n_edges + n_loops) return;
  const int h = tid & 3;
  int s, d;
  if (e < n_edges) { s = src[e]; d = dst[e]; }
  else { s = e - n_edges; d = s; }
  float ea = a_s[s * 4 + h] + a_d[d * 4 + h];
  ea = ea > 0.f ? ea : SLOPE * ea;
  atomicAdd(&den[d * 4 + h], __expf(ea));
}

// Pass 2: xacc[d,hc] += w * exp(e)/den[d,h] * h_src[s,hc]. One thread per (edge, 4 channels).
__global__ void scatter_kernel(const int* __restrict__ src, const int* __restrict__ dst,
    int n_edges, int n_loops, const float* __restrict__ a_s, const float* __restrict__ a_d,
    const float* __restrict__ den, const float* __restrict__ h_src, float w,
    float* __restrict__ xacc)
{
  const int tid = blockIdx.x * blockDim.x + threadIdx.x;
  const int e = tid >> 5;
  if (e >= n_edges + n_loops) return;
  const int q = tid & 31;       // 4-channel group 0..31
  const int h = q >> 3;         // head
  int s, d;
  if (e < n_edges) { s = src[e]; d = dst[e]; }
  else { s = e - n_edges; d = s; }
  float ea = a_s[s * 4 + h] + a_d[d * 4 + h];
  ea = ea > 0.f ? ea : SLOPE * ea;
  const float alpha = w * __expf(ea) / den[d * 4 + h];
  const float4 hv = *(const float4*)(h_src + (size_t)s * 128 + q * 4);
  float* base = xacc + (size_t)d * 128 + q * 4;
  atomicAdd(base + 0, alpha * hv.x);
  atomicAdd(base + 1, alpha * hv.y);
  atomicAdd(base + 2, alpha * hv.z);
  atomicAdd(base + 3, alpha * hv.w);
}

// x = relu(xacc + cbias + res)  (fp32, input to final GEMM)
__global__ void skip_relu_kernel(const float* __restrict__ xacc, const float* __restrict__ res,
    const float* __restrict__ cbias, float* __restrict__ x, int total4)
{
  const int i4 = blockIdx.x * blockDim.x + threadIdx.x;
  if (i4 >= total4) return;
  const size_t i = (size_t)i4 * 4;
  const int j = (int)(i & 127);
  const float4 a = *(const float4*)(xacc + i);
  const float4 r = *(const float4*)(res + i);
  const float4 b = *(const float4*)(cbias + j);
  float4 o;
  o.x = fmaxf(a.x + b.x + r.x, 0.f);
  o.y = fmaxf(a.y + b.y + r.y, 0.f);
  o.z = fmaxf(a.z + b.z + r.z, 0.f);
  o.w = fmaxf(a.w + b.w + r.w, 0.f);
  *(float4*)(x + i) = o;
}

extern "C" void kernel_launch(void* const* d_in, const int* in_sizes, int n_in,
                              void* d_out, int out_size, void* d_ws, size_t ws_size,
                              hipStream_t stream)
{
  const float* x_t   = (const float*)d_in[0];
  const float* x_c   = (const float*)d_in[1];
  const int*   e_tt  = (const int*)d_in[2];
  const int*   ect_s = (const int*)d_in[3];
  const int*   ect_d = (const int*)d_in[4];
  const float* Wpt = (const float*)d_in[5];   const float* bpt = (const float*)d_in[6];
  const float* Wpc = (const float*)d_in[7];   const float* bpc = (const float*)d_in[8];
  const float* Wsd = (const float*)d_in[9];   const float* As_sd = (const float*)d_in[10];
  const float* Ad_sd = (const float*)d_in[11]; const float* bsd = (const float*)d_in[12];
  const float* Wds = (const float*)d_in[13];  const float* As_ds = (const float*)d_in[14];
  const float* Ad_ds = (const float*)d_in[15]; const float* bds = (const float*)d_in[16];
  const float* Wcs = (const float*)d_in[17];  const float* Wcd = (const float*)d_in[18];
  const float* As_ct = (const float*)d_in[19]; const float* Ad_ct = (const float*)d_in[20];
  const float* bct = (const float*)d_in[21];
  const float* Wout = (const float*)d_in[22]; const float* bout = (const float*)d_in[23];

  // workspace layout (~171 MB)
  char* p = (char*)d_ws;
  size_t off = 0;
  float* h_t   = (float*)(p + off); off += (size_t)NT * 128 * 4;
  float* h_c   = (float*)(p + off); off += (size_t)NC * 128 * 4;
  float* hbuf  = (float*)(p + off); off += (size_t)NT * 128 * 4;
  float* xacc  = (float*)(p + off); off += (size_t)NT * 128 * 4;
  float* den   = (float*)(p + off); off += (size_t)NT * 4 * 4;
  float* a_s   = (float*)(p + off); off += (size_t)NT * 4 * 4;
  float* a_d   = (float*)(p + off); off += (size_t)NT * 4 * 4;
  float* folds = (float*)(p + off); off += (size_t)6 * 512 * 4;
  float* cbias = (float*)(p + off); off += 128 * 4;

  const int* tt_src = e_tt;
  const int* tt_dst = e_tt + ETT;

  const int gT = (NT + 31) / 32;     // 3125
  const int gC = (NC + 31) / 32;     // 782
  const int nE_tt = ETT + NT;        // edges + self loops
  const int gden_tt = (nE_tt * 4 + 255) / 256;
  const int gden_ct = (ECT * 4 + 255) / 256;
  const int gsc_tt = (int)(((size_t)nE_tt * 32 + 255) / 256);
  const int gsc_ct = (int)(((size_t)ECT * 32 + 255) / 256);
  const int nvec = (NT * 32 + 255) / 256;   // NT*128/4 work items

  // 1. pre-transforms (+relu)
  gemm_kernel<64><<<gT, 256, 0, stream>>>(x_t, Wpt, bpt, h_t, NT, 1);
  gemm_kernel<32><<<gC, 256, 0, stream>>>(x_c, Wpc, bpc, h_c, NC, 1);

  // 2. attention folds + combined bias
  fold_kernel<<<1, 128, 0, stream>>>(Wsd, As_sd, folds + 0 * 512);
  fold_kernel<<<1, 128, 0, stream>>>(Wsd, Ad_sd, folds + 1 * 512);
  fold_kernel<<<1, 128, 0, stream>>>(Wds, As_ds, folds + 2 * 512);
  fold_kernel<<<1, 128, 0, stream>>>(Wds, Ad_ds, folds + 3 * 512);
  fold_kernel<<<1, 128, 0, stream>>>(Wcs, As_ct, folds + 4 * 512);
  fold_kernel<<<1, 128, 0, stream>>>(Wcd, Ad_ct, folds + 5 * 512);
  cbias_kernel<<<1, 128, 0, stream>>>(bsd, bds, bct, cbias);
  hipMemsetAsync(xacc, 0, (size_t)NT * 128 * 4, stream);

  // 3. GAT sd (forward tt edges + self loops), weight 0.25
  gemm_kernel<128><<<gT, 256, 0, stream>>>(h_t, Wsd, (const float*)0, hbuf, NT, 0);
  node_att_kernel<<<gT, 128, 0, stream>>>(hbuf, folds + 0 * 512, folds + 1 * 512, a_s, a_d, NT);
  hipMemsetAsync(den, 0, (size_t)NT * 4 * 4, stream);
  den_kernel<<<gden_tt, 256, 0, stream>>>(tt_src, tt_dst, ETT, NT, a_s, a_d, den);
  scatter_kernel<<<gsc_tt, 256, 0, stream>>>(tt_src, tt_dst, ETT, NT, a_s, a_d, den, hbuf, 0.25f, xacc);

  // 4. GAT ds (reversed tt edges + self loops), weight 0.25
  gemm_kernel<128><<<gT, 256, 0, stream>>>(h_t, Wds, (const float*)0, hbuf, NT, 0);
  node_att_kernel<<<gT, 128, 0, stream>>>(hbuf, folds + 2 * 512, folds + 3 * 512, a_s, a_d, NT);
  hipMemsetAsync(den, 0, (size_t)NT * 4 * 4, stream);
  den_kernel<<<gden_tt, 256, 0, stream>>>(tt_dst, tt_src, ETT, NT, a_s, a_d, den);
  scatter_kernel<<<gsc_tt, 256, 0, stream>>>(tt_dst, tt_src, ETT, NT, a_s, a_d, den, hbuf, 0.25f, xacc);

  // 5. GAT ct (bipartite, no self loops), weight 0.5
  gemm_kernel<128><<<gC, 256, 0, stream>>>(h_c, Wcs, (const float*)0, hbuf, NC, 0);
  node_att_kernel<<<gC, 128, 0, stream>>>(hbuf, folds + 4 * 512, (const float*)0, a_s, (float*)0, NC);
  node_att_kernel<<<gT, 128, 0, stream>>>(h_t, (const float*)0, folds + 5 * 512, (float*)0, a_d, NT);
  hipMemsetAsync(den, 0, (size_t)NT * 4 * 4, stream);
  den_kernel<<<gden_ct, 256, 0, stream>>>(ect_s, ect_d, ECT, 0, a_s, a_d, den);
  scatter_kernel<<<gsc_ct, 256, 0, stream>>>(ect_s, ect_d, ECT, 0, a_s, a_d, den, hbuf, 0.5f, xacc);

  // 6. skip + relu -> x (reuse hbuf), final GEMM -> d_out
  skip_relu_kernel<<<nvec, 256, 0, stream>>>(xacc, h_t, cbias, hbuf, NT * 32);
  gemm_kernel<128><<<gT, 256, 0, stream>>>(hbuf, Wout, bout, (float*)d_out, NT, 0);
}

// Round 3
// 1253.520 us; speedup vs baseline: 3.4781x; 3.4781x over previous
//
#include <hip/hip_runtime.h>
#include <cstdint>
#include <cstddef>

#define NT 100000
#define NC 25000
#define ETT 800000
#define ECT 400000
#define SLOPE 0.2f

// out[N,128] = act(in[N,K] @ W[K,128] + bias). All fp32.
// Block=256: 32 rows x 128 cols; thread t -> row t>>3, cols (t&7)*4 + {0,32,64,96}.
// In-place safe (out==in): each block writes only the 32 rows it alone reads,
// and all its reads complete (syncthreads) before the epilogue writes.
template<int K>
__global__ __launch_bounds__(256) void gemm_kernel(const float* __restrict__ in,
    const float* __restrict__ W, const float* __restrict__ bias,
    float* __restrict__ out, int N, int relu)
{
  __shared__ float s_in[32][33];
  __shared__ float s_W[32][128];
  const int t = threadIdx.x;
  const int row0 = blockIdx.x * 32;
  const int rl = t >> 3;
  const int cg = t & 7;
  float acc[4][4];
  for (int g = 0; g < 4; ++g)
    for (int j = 0; j < 4; ++j)
      acc[g][j] = bias ? bias[g * 32 + cg * 4 + j] : 0.f;

  for (int kc = 0; kc < K; kc += 32) {
    {
      const int gr = row0 + rl;
      float4 f = make_float4(0.f, 0.f, 0.f, 0.f);
      if (gr < N)
        f = *(const float4*)(in + (size_t)gr * K + kc + cg * 4);
      s_in[rl][cg * 4 + 0] = f.x; s_in[rl][cg * 4 + 1] = f.y;
      s_in[rl][cg * 4 + 2] = f.z; s_in[rl][cg * 4 + 3] = f.w;
    }
    for (int j = 0; j < 4; ++j) {
      const int idx = t + j * 256;
      const int k = idx >> 5;
      const int c4 = (idx & 31) * 4;
      *(float4*)&s_W[k][c4] = *(const float4*)(W + (size_t)(kc + k) * 128 + c4);
    }
    __syncthreads();
#pragma unroll 8
    for (int k = 0; k < 32; ++k) {
      const float a = s_in[rl][k];
      for (int g = 0; g < 4; ++g) {
        const float4 w = *(const float4*)&s_W[k][g * 32 + cg * 4];
        acc[g][0] = fmaf(a, w.x, acc[g][0]);
        acc[g][1] = fmaf(a, w.y, acc[g][1]);
        acc[g][2] = fmaf(a, w.z, acc[g][2]);
        acc[g][3] = fmaf(a, w.w, acc[g][3]);
      }
    }
    __syncthreads();
  }
  const int gr = row0 + rl;
  if (gr < N) {
    for (int g = 0; g < 4; ++g) {
      float x0 = acc[g][0], x1 = acc[g][1], x2 = acc[g][2], x3 = acc[g][3];
      if (relu) { x0 = fmaxf(x0, 0.f); x1 = fmaxf(x1, 0.f); x2 = fmaxf(x2, 0.f); x3 = fmaxf(x3, 0.f); }
      *(float4*)(out + (size_t)gr * 128 + g * 32 + cg * 4) = make_float4(x0, x1, x2, x3);
    }
  }
}

// fold[k][h] = sum_c W[k, h*32+c] * att[h, c]
__global__ void fold_kernel(const float* __restrict__ W, const float* __restrict__ att,
                            float* __restrict__ fold)
{
  const int k = threadIdx.x;  // 128
  for (int h = 0; h < 4; ++h) {
    float s = 0.f;
    for (int c = 0; c < 32; ++c)
      s = fmaf(W[k * 128 + h * 32 + c], att[h * 32 + c], s);
    fold[k * 4 + h] = s;
  }
}

__global__ void cbias_kernel(const float* __restrict__ bsd, const float* __restrict__ bds,
                             const float* __restrict__ bct, float* __restrict__ cbias)
{
  const int j = threadIdx.x;  // 128
  cbias[j] = 0.25f * bsd[j] + 0.25f * bds[j] + 0.5f * bct[j];
}

// a[n,h] = sum_k h[n,k] * fold[k,h]
__global__ __launch_bounds__(128) void node_att_kernel(const float* __restrict__ h,
    const float* __restrict__ fold_s, const float* __restrict__ fold_d,
    float* __restrict__ a_s, float* __restrict__ a_d, int N)
{
  __shared__ float s_h[32][129];
  __shared__ float s_fs[512];
  __shared__ float s_fd[512];
  const int t = threadIdx.x;
  const int n0 = blockIdx.x * 32;
  for (int i = t; i < 512; i += 128) {
    s_fs[i] = fold_s ? fold_s[i] : 0.f;
    s_fd[i] = fold_d ? fold_d[i] : 0.f;
  }
  for (int r = 0; r < 32; ++r) {
    const int n = n0 + r;
    s_h[r][t] = (n < N) ? h[(size_t)n * 128 + t] : 0.f;
  }
  __syncthreads();
  const int nl = t >> 2, hh = t & 3;
  float ss = 0.f, sd = 0.f;
#pragma unroll 16
  for (int k = 0; k < 128; ++k) {
    const float v = s_h[nl][k];
    ss = fmaf(v, s_fs[k * 4 + hh], ss);
    sd = fmaf(v, s_fd[k * 4 + hh], sd);
  }
  const int n = n0 + nl;
  if (n < N) {
    if (a_s) a_s[n * 4 + hh] = ss;
    if (a_d) a_d[n * 4 + hh] = sd;
  }
}

// --- CSR build ---
__global__ void hist_tt_kernel(const int* __restrict__ src, const int* __restrict__ dst,
                               int* __restrict__ cnt_f, int* __restrict__ cnt_r)
{
  const int e = blockIdx.x * blockDim.x + threadIdx.x;
  if (e >= ETT) return;
  atomicAdd(&cnt_f[dst[e]], 1);
  atomicAdd(&cnt_r[src[e]], 1);
}

__global__ void hist_ct_kernel(const int* __restrict__ dst, int* __restrict__ cnt_c)
{
  const int e = blockIdx.x * blockDim.x + threadIdx.x;
  if (e >= ECT) return;
  atomicAdd(&cnt_c[dst[e]], 1);
}

// Exclusive scan of 3 count arrays (stride NT); writes off (stride NT+1) and cur.
__global__ __launch_bounds__(1024) void scan_kernel(const int* __restrict__ cnt_all,
    int* __restrict__ off_all, int* __restrict__ cur_all)
{
  const int a = blockIdx.x;
  const int* cnt = cnt_all + (size_t)a * NT;
  int* off = off_all + (size_t)a * (NT + 1);
  int* cur = cur_all + (size_t)a * NT;
  const int t = threadIdx.x;
  const int chunk = (NT + 1023) / 1024;  // 98
  const int lo = t * chunk;
  const int hi = min(lo + chunk, NT);
  int sum = 0;
  for (int i = lo; i < hi; ++i) sum += cnt[i];
  __shared__ int s[1024];
  s[t] = sum;
  __syncthreads();
  for (int d2 = 1; d2 < 1024; d2 <<= 1) {
    const int v = (t >= d2) ? s[t - d2] : 0;
    __syncthreads();
    s[t] += v;
    __syncthreads();
  }
  int run = (t == 0) ? 0 : s[t - 1];
  for (int i = lo; i < hi; ++i) { off[i] = run; cur[i] = run; run += cnt[i]; }
  if (t == 1023) off[NT] = run;
}

// Fill edge lists with the SOURCE node id (no edge-id indirection in gather).
__global__ void fill_tt_kernel(const int* __restrict__ src, const int* __restrict__ dst,
    int* __restrict__ cur_f, int* __restrict__ cur_r,
    int* __restrict__ el_f, int* __restrict__ el_r)
{
  const int e = blockIdx.x * blockDim.x + threadIdx.x;
  if (e >= ETT) return;
  const int s = src[e], d = dst[e];
  el_f[atomicAdd(&cur_f[d], 1)] = s;
  el_r[atomicAdd(&cur_r[s], 1)] = d;
}

__global__ void fill_ct_kernel(const int* __restrict__ src, const int* __restrict__ dst,
    int* __restrict__ cur_c, int* __restrict__ el_c)
{
  const int e = blockIdx.x * blockDim.x + threadIdx.x;
  if (e >= ECT) return;
  el_c[atomicAdd(&cur_c[dst[e]], 1)] = src[e];
}

// --- Fused GAT gather: one wave per dst node; lane owns channels (2l, 2l+1).
// Accumulates softmax numerator + denominator in registers; no atomics.
// MODE 0: x = w*res; MODE 1: x += w*res; MODE 2: x = relu(x + w*res + cbias + skip).
template<int MODE>
__global__ __launch_bounds__(256) void gather_kernel(
    const int* __restrict__ off, const int* __restrict__ el,
    const float* __restrict__ a_s, const float* __restrict__ a_d,
    const float* __restrict__ hsrc, float w, int self_loop,
    float* __restrict__ x, const float* __restrict__ skip,
    const float* __restrict__ cbias, int N)
{
  const int wave = threadIdx.x >> 6;
  const int lane = threadIdx.x & 63;
  const int d = blockIdx.x * 4 + wave;
  if (d >= N) return;
  const int h = lane >> 4;
  const int c0 = lane * 2;
  const float ad = a_d[d * 4 + h];
  float den = 0.f, acc0 = 0.f, acc1 = 0.f;
  const int beg = off[d], end = off[d + 1];
  for (int i = beg; i < end; ++i) {
    const int s = el[i];
    float ea = a_s[s * 4 + h] + ad;
    ea = ea > 0.f ? ea : SLOPE * ea;
    const float ex = __expf(ea);
    const float2 hv = *(const float2*)(hsrc + (size_t)s * 128 + c0);
    den += ex;
    acc0 = fmaf(ex, hv.x, acc0);
    acc1 = fmaf(ex, hv.y, acc1);
  }
  if (self_loop) {
    float ea = a_s[d * 4 + h] + ad;
    ea = ea > 0.f ? ea : SLOPE * ea;
    const float ex = __expf(ea);
    const float2 hv = *(const float2*)(hsrc + (size_t)d * 128 + c0);
    den += ex;
    acc0 = fmaf(ex, hv.x, acc0);
    acc1 = fmaf(ex, hv.y, acc1);
  }
  const float s_inv = den > 0.f ? w / den : 0.f;
  const float r0 = acc0 * s_inv, r1 = acc1 * s_inv;
  float* xp = x + (size_t)d * 128 + c0;
  if (MODE == 0) {
    *(float2*)xp = make_float2(r0, r1);
  } else if (MODE == 1) {
    float2 v = *(const float2*)xp;
    *(float2*)xp = make_float2(v.x + r0, v.y + r1);
  } else {
    const float2 v = *(const float2*)xp;
    const float2 sk = *(const float2*)(skip + (size_t)d * 128 + c0);
    const float2 cb = *(const float2*)(cbias + c0);
    *(float2*)xp = make_float2(fmaxf(v.x + r0 + cb.x + sk.x, 0.f),
                               fmaxf(v.y + r1 + cb.y + sk.y, 0.f));
  }
}

extern "C" void kernel_launch(void* const* d_in, const int* in_sizes, int n_in,
                              void* d_out, int out_size, void* d_ws, size_t ws_size,
                              hipStream_t stream)
{
  const float* x_t   = (const float*)d_in[0];
  const float* x_c   = (const float*)d_in[1];
  const int*   e_tt  = (const int*)d_in[2];
  const int*   ect_s = (const int*)d_in[3];
  const int*   ect_d = (const int*)d_in[4];
  const float* Wpt = (const float*)d_in[5];   const float* bpt = (const float*)d_in[6];
  const float* Wpc = (const float*)d_in[7];   const float* bpc = (const float*)d_in[8];
  const float* Wsd = (const float*)d_in[9];   const float* As_sd = (const float*)d_in[10];
  const float* Ad_sd = (const float*)d_in[11]; const float* bsd = (const float*)d_in[12];
  const float* Wds = (const float*)d_in[13];  const float* As_ds = (const float*)d_in[14];
  const float* Ad_ds = (const float*)d_in[15]; const float* bds = (const float*)d_in[16];
  const float* Wcs = (const float*)d_in[17];  const float* Wcd = (const float*)d_in[18];
  const float* As_ct = (const float*)d_in[19]; const float* Ad_ct = (const float*)d_in[20];
  const float* bct = (const float*)d_in[21];
  const float* Wout = (const float*)d_in[22]; const float* bout = (const float*)d_in[23];

  // workspace (~137 MB)
  char* p = (char*)d_ws;
  size_t off = 0;
  float* h_t   = (float*)(p + off); off += (size_t)NT * 128 * 4;
  float* hbuf  = (float*)(p + off); off += (size_t)NT * 128 * 4;   // hs, then hd
  float* hcs   = (float*)(p + off); off += (size_t)NC * 128 * 4;   // h_c, then h_c@Wcs (in-place)
  float* a_s_sd = (float*)(p + off); off += (size_t)NT * 4 * 4;
  float* a_d_sd = (float*)(p + off); off += (size_t)NT * 4 * 4;
  float* a_s_ds = (float*)(p + off); off += (size_t)NT * 4 * 4;
  float* a_d_ds = (float*)(p + off); off += (size_t)NT * 4 * 4;
  float* a_s_ct = (float*)(p + off); off += (size_t)NT * 4 * 4;    // only NC used
  float* a_d_ct = (float*)(p + off); off += (size_t)NT * 4 * 4;
  int* cnt = (int*)(p + off); off += (size_t)3 * NT * 4;           // f, r, c contiguous
  int* offs = (int*)(p + off); off += (size_t)3 * (NT + 1) * 4;
  int* cur = (int*)(p + off); off += (size_t)3 * NT * 4;
  int* el_f = (int*)(p + off); off += (size_t)ETT * 4;
  int* el_r = (int*)(p + off); off += (size_t)ETT * 4;
  int* el_c = (int*)(p + off); off += (size_t)ECT * 4;
  float* folds = (float*)(p + off); off += (size_t)6 * 512 * 4;
  float* cbias = (float*)(p + off); off += 128 * 4;

  int* cnt_f = cnt;           int* cnt_r = cnt + NT;          int* cnt_c = cnt + 2 * NT;
  int* off_f = offs;          int* off_r = offs + (NT + 1);   int* off_c = offs + 2 * (NT + 1);
  int* cur_f = cur;           int* cur_r = cur + NT;          int* cur_c = cur + 2 * NT;

  const int* tt_src = e_tt;
  const int* tt_dst = e_tt + ETT;

  const int gT = (NT + 31) / 32;
  const int gC = (NC + 31) / 32;
  const int gE_tt = (ETT + 255) / 256;
  const int gE_ct = (ECT + 255) / 256;
  const int gGat_t = (NT + 3) / 4;
  float* x = (float*)d_out;  // use d_out as the fused-GAT accumulator

  // CSR build
  hipMemsetAsync(cnt, 0, (size_t)3 * NT * 4, stream);
  hist_tt_kernel<<<gE_tt, 256, 0, stream>>>(tt_src, tt_dst, cnt_f, cnt_r);
  hist_ct_kernel<<<gE_ct, 256, 0, stream>>>(ect_d, cnt_c);
  scan_kernel<<<3, 1024, 0, stream>>>(cnt, offs, cur);
  fill_tt_kernel<<<gE_tt, 256, 0, stream>>>(tt_src, tt_dst, cur_f, cur_r, el_f, el_r);
  fill_ct_kernel<<<gE_ct, 256, 0, stream>>>(ect_s, ect_d, cur_c, el_c);

  // pre-transforms
  gemm_kernel<64><<<gT, 256, 0, stream>>>(x_t, Wpt, bpt, h_t, NT, 1);
  gemm_kernel<32><<<gC, 256, 0, stream>>>(x_c, Wpc, bpc, hcs, NC, 1);
  gemm_kernel<128><<<gC, 256, 0, stream>>>(hcs, Wcs, (const float*)0, hcs, NC, 0);  // in-place

  // folds + combined bias
  fold_kernel<<<1, 128, 0, stream>>>(Wsd, As_sd, folds + 0 * 512);
  fold_kernel<<<1, 128, 0, stream>>>(Wsd, Ad_sd, folds + 1 * 512);
  fold_kernel<<<1, 128, 0, stream>>>(Wds, As_ds, folds + 2 * 512);
  fold_kernel<<<1, 128, 0, stream>>>(Wds, Ad_ds, folds + 3 * 512);
  fold_kernel<<<1, 128, 0, stream>>>(Wcs, As_ct, folds + 4 * 512);
  fold_kernel<<<1, 128, 0, stream>>>(Wcd, Ad_ct, folds + 5 * 512);
  cbias_kernel<<<1, 128, 0, stream>>>(bsd, bds, bct, cbias);

  // ct attention logits (from hcs and h_t)
  node_att_kernel<<<gC, 128, 0, stream>>>(hcs, folds + 4 * 512, (const float*)0, a_s_ct, (float*)0, NC);
  node_att_kernel<<<gT, 128, 0, stream>>>(h_t, (const float*)0, folds + 5 * 512, (float*)0, a_d_ct, NT);

  // GAT sd: forward tt edges + self loops, weight 0.25  (x = 0.25*res)
  gemm_kernel<128><<<gT, 256, 0, stream>>>(h_t, Wsd, (const float*)0, hbuf, NT, 0);
  node_att_kernel<<<gT, 128, 0, stream>>>(hbuf, folds + 0 * 512, folds + 1 * 512, a_s_sd, a_d_sd, NT);
  gather_kernel<0><<<gGat_t, 256, 0, stream>>>(off_f, el_f, a_s_sd, a_d_sd, hbuf, 0.25f, 1,
                                               x, (const float*)0, (const float*)0, NT);

  // GAT ds: reversed tt edges + self loops, weight 0.25  (x += 0.25*res)
  gemm_kernel<128><<<gT, 256, 0, stream>>>(h_t, Wds, (const float*)0, hbuf, NT, 0);
  node_att_kernel<<<gT, 128, 0, stream>>>(hbuf, folds + 2 * 512, folds + 3 * 512, a_s_ds, a_d_ds, NT);
  gather_kernel<1><<<gGat_t, 256, 0, stream>>>(off_r, el_r, a_s_ds, a_d_ds, hbuf, 0.25f, 1,
                                               x, (const float*)0, (const float*)0, NT);

  // GAT ct: bipartite, no self loops, weight 0.5 + finalize (cbias + skip + relu)
  gather_kernel<2><<<gGat_t, 256, 0, stream>>>(off_c, el_c, a_s_ct, a_d_ct, hcs, 0.5f, 0,
                                               x, h_t, cbias, NT);

  // final GEMM, in-place on d_out
  gemm_kernel<128><<<gT, 256, 0, stream>>>(x, Wout, bout, (float*)d_out, NT, 0);
}

// Round 4
// 879.623 us; speedup vs baseline: 4.9565x; 1.4251x over previous
//
#include <hip/hip_runtime.h>
#include <cstdint>
#include <cstddef>

typedef unsigned short u16;
typedef unsigned int u32;

#define NT 100000
#define NC 25000
#define ETT 800000
#define ECT 400000
#define SLOPE 0.2f
#define NB_PER 49               // ceil(NT/2048) scan blocks per array
#define OFFS (NT + 4)           // padded stride for offset arrays (16B-aligned)

__device__ __forceinline__ u16 f2bf(float f) {
  u32 u = __float_as_uint(f);
  u32 r = (u >> 16) & 1u;
  return (u16)((u + 0x7fffu + r) >> 16);
}

// ---------- plain fp32 GEMM: out[N,128] = in[N,128] @ W + bias (K6) ----------
__global__ __launch_bounds__(256) void gemm_kernel(const float* __restrict__ in,
    const float* __restrict__ W, const float* __restrict__ bias,
    float* __restrict__ out, int N)
{
  __shared__ float s_in[32][33];
  __shared__ float s_W[32][128];
  const int t = threadIdx.x;
  const int row0 = blockIdx.x * 32;
  const int rl = t >> 3, cg = t & 7;
  float acc[4][4];
  for (int g = 0; g < 4; ++g)
    for (int j = 0; j < 4; ++j)
      acc[g][j] = bias[g * 32 + cg * 4 + j];
  const int gr = row0 + rl;
  for (int kc = 0; kc < 128; kc += 32) {
    {
      float4 f = make_float4(0.f, 0.f, 0.f, 0.f);
      if (gr < N) f = *(const float4*)(in + (size_t)gr * 128 + kc + cg * 4);
      s_in[rl][cg * 4 + 0] = f.x; s_in[rl][cg * 4 + 1] = f.y;
      s_in[rl][cg * 4 + 2] = f.z; s_in[rl][cg * 4 + 3] = f.w;
    }
    for (int j = 0; j < 4; ++j) {
      const int idx = t + j * 256;
      const int k = idx >> 5, c4 = (idx & 31) * 4;
      *(float4*)&s_W[k][c4] = *(const float4*)(W + (size_t)(kc + k) * 128 + c4);
    }
    __syncthreads();
#pragma unroll 8
    for (int k = 0; k < 32; ++k) {
      const float a = s_in[rl][k];
      for (int g = 0; g < 4; ++g) {
        const float4 w = *(const float4*)&s_W[k][g * 32 + cg * 4];
        acc[g][0] = fmaf(a, w.x, acc[g][0]);
        acc[g][1] = fmaf(a, w.y, acc[g][1]);
        acc[g][2] = fmaf(a, w.z, acc[g][2]);
        acc[g][3] = fmaf(a, w.w, acc[g][3]);
      }
    }
    __syncthreads();
  }
  if (gr < N)
    for (int g = 0; g < 4; ++g)
      *(float4*)(out + (size_t)gr * 128 + g * 32 + cg * 4) =
          make_float4(acc[g][0], acc[g][1], acc[g][2], acc[g][3]);
}

// ---------- K1: h_t = relu(x_t @ Wpt + b); a_d_ct = h_t @ fold_cd ----------
__global__ __launch_bounds__(256) void pre_t_kernel(const float* __restrict__ in,
    const float* __restrict__ W, const float* __restrict__ bias,
    const float* __restrict__ fold_cd, float* __restrict__ h_t,
    float* __restrict__ aD, int N)
{
  __shared__ float s_in[32][33];
  __shared__ float s_W[32][128];
  __shared__ float s_fold[512];
  const int t = threadIdx.x;
  s_fold[t] = fold_cd[t];
  s_fold[t + 256] = fold_cd[t + 256];
  const int row0 = blockIdx.x * 32;
  const int rl = t >> 3, cg = t & 7;
  const int gr = row0 + rl;
  float acc[4][4];
  for (int g = 0; g < 4; ++g)
    for (int j = 0; j < 4; ++j)
      acc[g][j] = bias[g * 32 + cg * 4 + j];
  for (int kc = 0; kc < 64; kc += 32) {
    {
      float4 f = make_float4(0.f, 0.f, 0.f, 0.f);
      if (gr < N) f = *(const float4*)(in + (size_t)gr * 64 + kc + cg * 4);
      s_in[rl][cg * 4 + 0] = f.x; s_in[rl][cg * 4 + 1] = f.y;
      s_in[rl][cg * 4 + 2] = f.z; s_in[rl][cg * 4 + 3] = f.w;
    }
    for (int j = 0; j < 4; ++j) {
      const int idx = t + j * 256;
      const int k = idx >> 5, c4 = (idx & 31) * 4;
      *(float4*)&s_W[k][c4] = *(const float4*)(W + (size_t)(kc + k) * 128 + c4);
    }
    __syncthreads();
#pragma unroll 8
    for (int k = 0; k < 32; ++k) {
      const float a = s_in[rl][k];
      for (int g = 0; g < 4; ++g) {
        const float4 w = *(const float4*)&s_W[k][g * 32 + cg * 4];
        acc[g][0] = fmaf(a, w.x, acc[g][0]);
        acc[g][1] = fmaf(a, w.y, acc[g][1]);
        acc[g][2] = fmaf(a, w.z, acc[g][2]);
        acc[g][3] = fmaf(a, w.w, acc[g][3]);
      }
    }
    __syncthreads();
  }
  if (gr < N) {
    float p0 = 0.f, p1 = 0.f, p2 = 0.f, p3 = 0.f;
    for (int g = 0; g < 4; ++g) {
      for (int j = 0; j < 4; ++j) acc[g][j] = fmaxf(acc[g][j], 0.f);
      *(float4*)(h_t + (size_t)gr * 128 + g * 32 + cg * 4) =
          make_float4(acc[g][0], acc[g][1], acc[g][2], acc[g][3]);
      for (int j = 0; j < 4; ++j) {
        const int col = g * 32 + cg * 4 + j;
        const float4 f4 = *(const float4*)&s_fold[col * 4];
        const float a = acc[g][j];
        p0 = fmaf(a, f4.x, p0); p1 = fmaf(a, f4.y, p1);
        p2 = fmaf(a, f4.z, p2); p3 = fmaf(a, f4.w, p3);
      }
    }
    for (int m = 1; m < 8; m <<= 1) {
      p0 += __shfl_xor(p0, m); p1 += __shfl_xor(p1, m);
      p2 += __shfl_xor(p2, m); p3 += __shfl_xor(p3, m);
    }
    if (cg == 0) *(float4*)(aD + (size_t)gr * 4) = make_float4(p0, p1, p2, p3);
  }
}

// ---------- K2/K3: out_bf = in @ W (bf16); aS/aD logits in epilogue ----------
__global__ __launch_bounds__(256) void gemm_logits_kernel(const float* __restrict__ in,
    const float* __restrict__ W, const float* __restrict__ attS,
    const float* __restrict__ attD, u16* __restrict__ out_bf,
    float* __restrict__ aS, float* __restrict__ aD, int N)
{
  __shared__ float s_in[32][33];
  __shared__ float s_W[32][128];
  const int t = threadIdx.x;
  const int row0 = blockIdx.x * 32;
  const int rl = t >> 3, cg = t & 7;
  const int gr = row0 + rl;
  float acc[4][4];
  for (int g = 0; g < 4; ++g)
    for (int j = 0; j < 4; ++j) acc[g][j] = 0.f;
  for (int kc = 0; kc < 128; kc += 32) {
    {
      float4 f = make_float4(0.f, 0.f, 0.f, 0.f);
      if (gr < N) f = *(const float4*)(in + (size_t)gr * 128 + kc + cg * 4);
      s_in[rl][cg * 4 + 0] = f.x; s_in[rl][cg * 4 + 1] = f.y;
      s_in[rl][cg * 4 + 2] = f.z; s_in[rl][cg * 4 + 3] = f.w;
    }
    for (int j = 0; j < 4; ++j) {
      const int idx = t + j * 256;
      const int k = idx >> 5, c4 = (idx & 31) * 4;
      *(float4*)&s_W[k][c4] = *(const float4*)(W + (size_t)(kc + k) * 128 + c4);
    }
    __syncthreads();
#pragma unroll 8
    for (int k = 0; k < 32; ++k) {
      const float a = s_in[rl][k];
      for (int g = 0; g < 4; ++g) {
        const float4 w = *(const float4*)&s_W[k][g * 32 + cg * 4];
        acc[g][0] = fmaf(a, w.x, acc[g][0]);
        acc[g][1] = fmaf(a, w.y, acc[g][1]);
        acc[g][2] = fmaf(a, w.z, acc[g][2]);
        acc[g][3] = fmaf(a, w.w, acc[g][3]);
      }
    }
    __syncthreads();
  }
  if (gr < N) {
    float pS[4], pD[4];
    for (int g = 0; g < 4; ++g) {
      u32 lo = (u32)f2bf(acc[g][0]) | ((u32)f2bf(acc[g][1]) << 16);
      u32 hi = (u32)f2bf(acc[g][2]) | ((u32)f2bf(acc[g][3]) << 16);
      uint2 pk; pk.x = lo; pk.y = hi;
      *(uint2*)(out_bf + (size_t)gr * 128 + g * 32 + cg * 4) = pk;
      const float4 as4 = *(const float4*)(attS + g * 32 + cg * 4);
      const float4 ad4 = *(const float4*)(attD + g * 32 + cg * 4);
      pS[g] = acc[g][0] * as4.x + acc[g][1] * as4.y + acc[g][2] * as4.z + acc[g][3] * as4.w;
      pD[g] = acc[g][0] * ad4.x + acc[g][1] * ad4.y + acc[g][2] * ad4.z + acc[g][3] * ad4.w;
    }
    for (int m = 1; m < 8; m <<= 1)
      for (int g = 0; g < 4; ++g) {
        pS[g] += __shfl_xor(pS[g], m);
        pD[g] += __shfl_xor(pD[g], m);
      }
    if (cg == 0) {
      *(float4*)(aS + (size_t)gr * 4) = make_float4(pS[0], pS[1], pS[2], pS[3]);
      *(float4*)(aD + (size_t)gr * 4) = make_float4(pD[0], pD[1], pD[2], pD[3]);
    }
  }
}

// ---------- K4: hcs = relu(x_c @ Wpc + b) @ Wcs (bf16) + a_s_ct ----------
__global__ __launch_bounds__(256) void ctx_kernel(const float* __restrict__ x_c,
    const float* __restrict__ Wpc, const float* __restrict__ bpc,
    const float* __restrict__ Wcs, const float* __restrict__ attS,
    u16* __restrict__ hc_bf, float* __restrict__ aS, int N)
{
  __shared__ float s_in[32][33];
  __shared__ float s_W[32][128];
  __shared__ float s_h[32][132];
  const int t = threadIdx.x;
  const int row0 = blockIdx.x * 32;
  const int rl = t >> 3, cg = t & 7;
  const int gr = row0 + rl;
  // stage 1: K=32
  {
    float4 f = make_float4(0.f, 0.f, 0.f, 0.f);
    if (gr < N) f = *(const float4*)(x_c + (size_t)gr * 32 + cg * 4);
    s_in[rl][cg * 4 + 0] = f.x; s_in[rl][cg * 4 + 1] = f.y;
    s_in[rl][cg * 4 + 2] = f.z; s_in[rl][cg * 4 + 3] = f.w;
  }
  for (int j = 0; j < 4; ++j) {
    const int idx = t + j * 256;
    const int k = idx >> 5, c4 = (idx & 31) * 4;
    *(float4*)&s_W[k][c4] = *(const float4*)(Wpc + (size_t)k * 128 + c4);
  }
  __syncthreads();
  float acc[4][4];
  for (int g = 0; g < 4; ++g)
    for (int j = 0; j < 4; ++j) acc[g][j] = bpc[g * 32 + cg * 4 + j];
#pragma unroll 8
  for (int k = 0; k < 32; ++k) {
    const float a = s_in[rl][k];
    for (int g = 0; g < 4; ++g) {
      const float4 w = *(const float4*)&s_W[k][g * 32 + cg * 4];
      acc[g][0] = fmaf(a, w.x, acc[g][0]);
      acc[g][1] = fmaf(a, w.y, acc[g][1]);
      acc[g][2] = fmaf(a, w.z, acc[g][2]);
      acc[g][3] = fmaf(a, w.w, acc[g][3]);
    }
  }
  for (int g = 0; g < 4; ++g)
    *(float4*)&s_h[rl][g * 32 + cg * 4] =
        make_float4(fmaxf(acc[g][0], 0.f), fmaxf(acc[g][1], 0.f),
                    fmaxf(acc[g][2], 0.f), fmaxf(acc[g][3], 0.f));
  __syncthreads();
  // stage 2: K=128 from LDS
  float acc2[4][4];
  for (int g = 0; g < 4; ++g)
    for (int j = 0; j < 4; ++j) acc2[g][j] = 0.f;
  for (int kc = 0; kc < 128; kc += 32) {
    for (int j = 0; j < 4; ++j) {
      const int idx = t + j * 256;
      const int k = idx >> 5, c4 = (idx & 31) * 4;
      *(float4*)&s_W[k][c4] = *(const float4*)(Wcs + (size_t)(kc + k) * 128 + c4);
    }
    __syncthreads();
#pragma unroll 8
    for (int k = 0; k < 32; ++k) {
      const float a = s_h[rl][kc + k];
      for (int g = 0; g < 4; ++g) {
        const float4 w = *(const float4*)&s_W[k][g * 32 + cg * 4];
        acc2[g][0] = fmaf(a, w.x, acc2[g][0]);
        acc2[g][1] = fmaf(a, w.y, acc2[g][1]);
        acc2[g][2] = fmaf(a, w.z, acc2[g][2]);
        acc2[g][3] = fmaf(a, w.w, acc2[g][3]);
      }
    }
    __syncthreads();
  }
  if (gr < N) {
    float pS[4];
    for (int g = 0; g < 4; ++g) {
      u32 lo = (u32)f2bf(acc2[g][0]) | ((u32)f2bf(acc2[g][1]) << 16);
      u32 hi = (u32)f2bf(acc2[g][2]) | ((u32)f2bf(acc2[g][3]) << 16);
      uint2 pk; pk.x = lo; pk.y = hi;
      *(uint2*)(hc_bf + (size_t)gr * 128 + g * 32 + cg * 4) = pk;
      const float4 as4 = *(const float4*)(attS + g * 32 + cg * 4);
      pS[g] = acc2[g][0] * as4.x + acc2[g][1] * as4.y + acc2[g][2] * as4.z + acc2[g][3] * as4.w;
    }
    for (int m = 1; m < 8; m <<= 1)
      for (int g = 0; g < 4; ++g) pS[g] += __shfl_xor(pS[g], m);
    if (cg == 0)
      *(float4*)(aS + (size_t)gr * 4) = make_float4(pS[0], pS[1], pS[2], pS[3]);
  }
}

// ---------- fold_cd + combined bias (1 dispatch, 2 blocks) ----------
__global__ void fold_all_kernel(const float* __restrict__ Wcd, const float* __restrict__ attD,
    const float* __restrict__ bsd, const float* __restrict__ bds, const float* __restrict__ bct,
    float* __restrict__ fold_cd, float* __restrict__ cbias)
{
  const int k = threadIdx.x;  // 128
  if (blockIdx.x == 0) {
    for (int h = 0; h < 4; ++h) {
      float s = 0.f;
      for (int c = 0; c < 32; ++c)
        s = fmaf(Wcd[k * 128 + h * 32 + c], attD[h * 32 + c], s);
      fold_cd[k * 4 + h] = s;
    }
  } else {
    cbias[k] = 0.25f * bsd[k] + 0.25f * bds[k] + 0.5f * bct[k];
  }
}

// ---------- CSR build ----------
__global__ void hist_all_kernel(const int* __restrict__ tt_src, const int* __restrict__ tt_dst,
    const int* __restrict__ ect_d, int* __restrict__ cnt_f, int* __restrict__ cnt_r,
    int* __restrict__ cnt_c)
{
  const int e = blockIdx.x * blockDim.x + threadIdx.x;
  if (e < ETT) {
    atomicAdd(&cnt_f[tt_dst[e]], 1);
    atomicAdd(&cnt_r[tt_src[e]], 1);
  }
  if (e < ECT) atomicAdd(&cnt_c[ect_d[e]], 1);
}

// scan phase B: per-block local exclusive scan; bsum[b] = block total
__global__ __launch_bounds__(256) void scan_blk_kernel(const int* __restrict__ cnt,
    int* __restrict__ off, int* __restrict__ bsum)
{
  const int a = blockIdx.x / NB_PER;
  const int b = blockIdx.x % NB_PER;
  const int t = threadIdx.x;
  const int* c = cnt + (size_t)a * NT;
  int* o = off + (size_t)a * OFFS;
  const int idx = b * 2048 + t * 8;
  int v[8];
  int s = 0;
  if (idx < NT) {
    const int4 q0 = *(const int4*)(c + idx);
    const int4 q1 = *(const int4*)(c + idx + 4);
    int x;
    x = q0.x; v[0] = s; s += x;  x = q0.y; v[1] = s; s += x;
    x = q0.z; v[2] = s; s += x;  x = q0.w; v[3] = s; s += x;
    x = q1.x; v[4] = s; s += x;  x = q1.y; v[5] = s; s += x;
    x = q1.z; v[6] = s; s += x;  x = q1.w; v[7] = s; s += x;
  } else {
    for (int j = 0; j < 8; ++j) v[j] = 0;
  }
  __shared__ int sh[256];
  sh[t] = s;
  __syncthreads();
  for (int d = 1; d < 256; d <<= 1) {
    const int u = (t >= d) ? sh[t - d] : 0;
    __syncthreads();
    sh[t] += u;
    __syncthreads();
  }
  const int excl = (t == 0) ? 0 : sh[t - 1];
  if (idx < NT) {
    int4 q0, q1;
    q0.x = excl + v[0]; q0.y = excl + v[1]; q0.z = excl + v[2]; q0.w = excl + v[3];
    q1.x = excl + v[4]; q1.y = excl + v[5]; q1.z = excl + v[6]; q1.w = excl + v[7];
    *(int4*)(o + idx) = q0;
    *(int4*)(o + idx + 4) = q1;
  }
  if (t == 255) bsum[blockIdx.x] = sh[255];
}

// scan phase C: scan the 3x49 block sums (one wave per array); writes off[NT]
__global__ __launch_bounds__(192) void scan_top_kernel(const int* __restrict__ bsum,
    int* __restrict__ bpre, int* __restrict__ off)
{
  const int t = threadIdx.x;
  const int w = t >> 6, lane = t & 63;
  if (w >= 3) return;
  const int orig = (lane < NB_PER) ? bsum[w * NB_PER + lane] : 0;
  int v = orig;
  for (int d = 1; d < 64; d <<= 1) {
    const int u = __shfl_up(v, d);
    if (lane >= d) v += u;
  }
  if (lane < NB_PER) bpre[w * NB_PER + lane] = v - orig;
  if (lane == NB_PER - 1) off[(size_t)w * OFFS + NT] = v;
}

// scan phase D: add block prefix; materialize cur (aliased onto cnt)
__global__ __launch_bounds__(256) void scan_add_kernel(const int* __restrict__ bpre,
    int* __restrict__ off, int* __restrict__ cur)
{
  const int a = blockIdx.x / NB_PER;
  const int b = blockIdx.x % NB_PER;
  const int t = threadIdx.x;
  const int bp = bpre[blockIdx.x];
  int* o = off + (size_t)a * OFFS;
  int* cu = cur + (size_t)a * NT;
  const int idx = b * 2048 + t * 8;
  if (idx < NT) {
    int4 q0 = *(const int4*)(o + idx);
    int4 q1 = *(const int4*)(o + idx + 4);
    q0.x += bp; q0.y += bp; q0.z += bp; q0.w += bp;
    q1.x += bp; q1.y += bp; q1.z += bp; q1.w += bp;
    *(int4*)(o + idx) = q0;     *(int4*)(o + idx + 4) = q1;
    *(int4*)(cu + idx) = q0;    *(int4*)(cu + idx + 4) = q1;
  }
}

__global__ void fill_all_kernel(const int* __restrict__ tt_src, const int* __restrict__ tt_dst,
    const int* __restrict__ ect_s, const int* __restrict__ ect_d,
    int* __restrict__ cur_f, int* __restrict__ cur_r, int* __restrict__ cur_c,
    int* __restrict__ el_f, int* __restrict__ el_r, int* __restrict__ el_c)
{
  const int e = blockIdx.x * blockDim.x + threadIdx.x;
  if (e < ETT) {
    const int s = tt_src[e], d = tt_dst[e];
    el_f[atomicAdd(&cur_f[d], 1)] = s;
    el_r[atomicAdd(&cur_r[s], 1)] = d;
  }
  if (e < ECT)
    el_c[atomicAdd(&cur_c[ect_d[e]], 1)] = ect_s[e];
}

// ---------- K5: fused 3-relation gather, one wave per dst ----------
__device__ __forceinline__ void gat_accum(const int* __restrict__ off,
    const int* __restrict__ el, const float* __restrict__ aS, const float* __restrict__ aD,
    const u16* __restrict__ hb, int d, int h, int c0, int self_loop, float w,
    float& x0, float& x1)
{
  const float ad = aD[(size_t)d * 4 + h];
  float den = 0.f, a0 = 0.f, a1 = 0.f;
  const int beg = off[d], end = off[d + 1];
  for (int i = beg; i < end; ++i) {
    const int s = el[i];
    float ea = aS[(size_t)s * 4 + h] + ad;
    ea = ea > 0.f ? ea : SLOPE * ea;
    const float ex = __expf(ea);
    const u32 pk = *(const u32*)(hb + (size_t)s * 128 + c0);
    den += ex;
    a0 = fmaf(ex, __uint_as_float(pk << 16), a0);
    a1 = fmaf(ex, __uint_as_float(pk & 0xffff0000u), a1);
  }
  if (self_loop) {
    float ea = aS[(size_t)d * 4 + h] + ad;
    ea = ea > 0.f ? ea : SLOPE * ea;
    const float ex = __expf(ea);
    const u32 pk = *(const u32*)(hb + (size_t)d * 128 + c0);
    den += ex;
    a0 = fmaf(ex, __uint_as_float(pk << 16), a0);
    a1 = fmaf(ex, __uint_as_float(pk & 0xffff0000u), a1);
  }
  const float inv = den > 0.f ? w / den : 0.f;
  x0 = fmaf(a0, inv, x0);
  x1 = fmaf(a1, inv, x1);
}

__global__ __launch_bounds__(256) void gather_all_kernel(
    const int* __restrict__ off_f, const int* __restrict__ el_f,
    const float* __restrict__ aS_sd, const float* __restrict__ aD_sd, const u16* __restrict__ hs,
    const int* __restrict__ off_r, const int* __restrict__ el_r,
    const float* __restrict__ aS_ds, const float* __restrict__ aD_ds, const u16* __restrict__ hd,
    const int* __restrict__ off_c, const int* __restrict__ el_c,
    const float* __restrict__ aS_ct, const float* __restrict__ aD_ct, const u16* __restrict__ hc,
    const float* __restrict__ skip, const float* __restrict__ cbias, float* __restrict__ x)
{
  const int d = blockIdx.x * 4 + (threadIdx.x >> 6);
  if (d >= NT) return;
  const int lane = threadIdx.x & 63;
  const int h = lane >> 4;
  const int c0 = lane * 2;
  float x0 = 0.f, x1 = 0.f;
  gat_accum(off_f, el_f, aS_sd, aD_sd, hs, d, h, c0, 1, 0.25f, x0, x1);
  gat_accum(off_r, el_r, aS_ds, aD_ds, hd, d, h, c0, 1, 0.25f, x0, x1);
  gat_accum(off_c, el_c, aS_ct, aD_ct, hc, d, h, c0, 0, 0.5f, x0, x1);
  const float2 sk = *(const float2*)(skip + (size_t)d * 128 + c0);
  const float2 cb = *(const float2*)(cbias + c0);
  *(float2*)(x + (size_t)d * 128 + c0) =
      make_float2(fmaxf(x0 + cb.x + sk.x, 0.f), fmaxf(x1 + cb.y + sk.y, 0.f));
}

extern "C" void kernel_launch(void* const* d_in, const int* in_sizes, int n_in,
                              void* d_out, int out_size, void* d_ws, size_t ws_size,
                              hipStream_t stream)
{
  const float* x_t   = (const float*)d_in[0];
  const float* x_c   = (const float*)d_in[1];
  const int*   e_tt  = (const int*)d_in[2];
  const int*   ect_s = (const int*)d_in[3];
  const int*   ect_d = (const int*)d_in[4];
  const float* Wpt = (const float*)d_in[5];   const float* bpt = (const float*)d_in[6];
  const float* Wpc = (const float*)d_in[7];   const float* bpc = (const float*)d_in[8];
  const float* Wsd = (const float*)d_in[9];   const float* As_sd = (const float*)d_in[10];
  const float* Ad_sd = (const float*)d_in[11]; const float* bsd = (const float*)d_in[12];
  const float* Wds = (const float*)d_in[13];  const float* As_ds = (const float*)d_in[14];
  const float* Ad_ds = (const float*)d_in[15]; const float* bds = (const float*)d_in[16];
  const float* Wcs = (const float*)d_in[17];  const float* Wcd = (const float*)d_in[18];
  const float* As_ct = (const float*)d_in[19]; const float* Ad_ct = (const float*)d_in[20];
  const float* bct = (const float*)d_in[21];
  const float* Wout = (const float*)d_in[22]; const float* bout = (const float*)d_in[23];

  // workspace (~126 MB)
  char* p = (char*)d_ws;
  size_t off = 0;
  auto alloc = [&](size_t bytes) { char* r = p + off; off += (bytes + 255) & ~(size_t)255; return r; };
  float* h_t   = (float*)alloc((size_t)NT * 128 * 4);
  u16* hs_bf   = (u16*)alloc((size_t)NT * 128 * 2);
  u16* hd_bf   = (u16*)alloc((size_t)NT * 128 * 2);
  u16* hc_bf   = (u16*)alloc((size_t)NC * 128 * 2);
  float* aS_sd = (float*)alloc((size_t)NT * 4 * 4);
  float* aD_sd = (float*)alloc((size_t)NT * 4 * 4);
  float* aS_ds = (float*)alloc((size_t)NT * 4 * 4);
  float* aD_ds = (float*)alloc((size_t)NT * 4 * 4);
  float* aS_ct = (float*)alloc((size_t)NC * 4 * 4);
  float* aD_ct = (float*)alloc((size_t)NT * 4 * 4);
  int* cnt  = (int*)alloc((size_t)3 * NT * 4);          // reused as cur after scan
  int* offs = (int*)alloc((size_t)3 * OFFS * 4);
  int* el_f = (int*)alloc((size_t)ETT * 4);
  int* el_r = (int*)alloc((size_t)ETT * 4);
  int* el_c = (int*)alloc((size_t)ECT * 4);
  int* bsum = (int*)alloc((size_t)3 * NB_PER * 4);
  int* bpre = (int*)alloc((size_t)3 * NB_PER * 4);
  float* fold_cd = (float*)alloc(512 * 4);
  float* cbias   = (float*)alloc(128 * 4);

  int* cnt_f = cnt;          int* cnt_r = cnt + NT;         int* cnt_c = cnt + 2 * NT;
  int* off_f = offs;         int* off_r = offs + OFFS;      int* off_c = offs + 2 * OFFS;

  const int* tt_src = e_tt;
  const int* tt_dst = e_tt + ETT;

  const int gT = (NT + 31) / 32;   // 3125
  const int gC = (NC + 31) / 32;   // 782
  const int gE = (ETT + 255) / 256;
  float* x = (float*)d_out;

  // CSR build
  hipMemsetAsync(cnt, 0, (size_t)3 * NT * 4, stream);
  hist_all_kernel<<<gE, 256, 0, stream>>>(tt_src, tt_dst, ect_d, cnt_f, cnt_r, cnt_c);
  scan_blk_kernel<<<3 * NB_PER, 256, 0, stream>>>(cnt, offs, bsum);
  scan_top_kernel<<<1, 192, 0, stream>>>(bsum, bpre, offs);
  scan_add_kernel<<<3 * NB_PER, 256, 0, stream>>>(bpre, offs, cnt);
  fill_all_kernel<<<gE, 256, 0, stream>>>(tt_src, tt_dst, ect_s, ect_d,
                                          cnt_f, cnt_r, cnt_c, el_f, el_r, el_c);

  // fold_cd + combined bias (needed by pre_t / gather)
  fold_all_kernel<<<2, 128, 0, stream>>>(Wcd, Ad_ct, bsd, bds, bct, fold_cd, cbias);

  // node transforms with fused logits
  pre_t_kernel<<<gT, 256, 0, stream>>>(x_t, Wpt, bpt, fold_cd, h_t, aD_ct, NT);
  gemm_logits_kernel<<<gT, 256, 0, stream>>>(h_t, Wsd, As_sd, Ad_sd, hs_bf, aS_sd, aD_sd, NT);
  gemm_logits_kernel<<<gT, 256, 0, stream>>>(h_t, Wds, As_ds, Ad_ds, hd_bf, aS_ds, aD_ds, NT);
  ctx_kernel<<<gC, 256, 0, stream>>>(x_c, Wpc, bpc, Wcs, As_ct, hc_bf, aS_ct, NC);

  // fused gather (sd + ds + ct + cbias + skip + relu) -> x (= d_out)
  gather_all_kernel<<<(NT + 3) / 4, 256, 0, stream>>>(
      off_f, el_f, aS_sd, aD_sd, hs_bf,
      off_r, el_r, aS_ds, aD_ds, hd_bf,
      off_c, el_c, aS_ct, aD_ct, hc_bf,
      h_t, cbias, x);

  // final GEMM, in-place on d_out
  gemm_kernel<<<gT, 256, 0, stream>>>(x, Wout, bout, (float*)d_out, NT);
}

// Round 5
// 698.057 us; speedup vs baseline: 6.2457x; 1.2601x over previous
//
#include <hip/hip_runtime.h>
#include <cstdint>
#include <cstddef>

typedef unsigned short u16;
typedef unsigned int u32;

#define NT 100000
#define NC 25000
#define ETT 800000
#define ECT 400000
#define SLOPE 0.2f
#define NB_PER 49               // ceil(NT/2048) scan blocks per array
#define OFFS (NT + 4)           // padded stride for offset arrays (16B-aligned)

typedef __attribute__((ext_vector_type(8))) short bf16x8;
typedef __attribute__((ext_vector_type(4))) float f32x4;

__device__ __forceinline__ u16 f2bf(float f) {
  u32 u = __float_as_uint(f);
  u32 r = (u >> 16) & 1u;
  return (u16)((u + 0x7fffu + r) >> 16);
}
__device__ __forceinline__ float lof(u32 p) { return __uint_as_float(p << 16); }
__device__ __forceinline__ float hif(u32 p) { return __uint_as_float(p & 0xffff0000u); }

// ---------- K1: h_t(bf16) = relu(x_t @ Wpt + b); aD_ct = relu(h_t) @ fold_cd ----------
__global__ __launch_bounds__(256) void pre_t_kernel(const float* __restrict__ in,
    const float* __restrict__ W, const float* __restrict__ bias,
    const float* __restrict__ fold_cd, u16* __restrict__ h_t,
    float* __restrict__ aD, int N)
{
  __shared__ float s_in[32][33];
  __shared__ float s_W[32][128];
  __shared__ float s_fold[512];
  const int t = threadIdx.x;
  s_fold[t] = fold_cd[t];
  s_fold[t + 256] = fold_cd[t + 256];
  const int row0 = blockIdx.x * 32;
  const int rl = t >> 3, cg = t & 7;
  const int gr = row0 + rl;
  float acc[4][4];
  for (int g = 0; g < 4; ++g)
    for (int j = 0; j < 4; ++j)
      acc[g][j] = bias[g * 32 + cg * 4 + j];
  for (int kc = 0; kc < 64; kc += 32) {
    {
      float4 f = make_float4(0.f, 0.f, 0.f, 0.f);
      if (gr < N) f = *(const float4*)(in + (size_t)gr * 64 + kc + cg * 4);
      s_in[rl][cg * 4 + 0] = f.x; s_in[rl][cg * 4 + 1] = f.y;
      s_in[rl][cg * 4 + 2] = f.z; s_in[rl][cg * 4 + 3] = f.w;
    }
    for (int j = 0; j < 4; ++j) {
      const int idx = t + j * 256;
      const int k = idx >> 5, c4 = (idx & 31) * 4;
      *(float4*)&s_W[k][c4] = *(const float4*)(W + (size_t)(kc + k) * 128 + c4);
    }
    __syncthreads();
#pragma unroll 8
    for (int k = 0; k < 32; ++k) {
      const float a = s_in[rl][k];
      for (int g = 0; g < 4; ++g) {
        const float4 w = *(const float4*)&s_W[k][g * 32 + cg * 4];
        acc[g][0] = fmaf(a, w.x, acc[g][0]);
        acc[g][1] = fmaf(a, w.y, acc[g][1]);
        acc[g][2] = fmaf(a, w.z, acc[g][2]);
        acc[g][3] = fmaf(a, w.w, acc[g][3]);
      }
    }
    __syncthreads();
  }
  if (gr < N) {
    float p0 = 0.f, p1 = 0.f, p2 = 0.f, p3 = 0.f;
    for (int g = 0; g < 4; ++g) {
      for (int j = 0; j < 4; ++j) acc[g][j] = fmaxf(acc[g][j], 0.f);
      uint2 pk;
      pk.x = (u32)f2bf(acc[g][0]) | ((u32)f2bf(acc[g][1]) << 16);
      pk.y = (u32)f2bf(acc[g][2]) | ((u32)f2bf(acc[g][3]) << 16);
      *(uint2*)(h_t + (size_t)gr * 128 + g * 32 + cg * 4) = pk;
      for (int j = 0; j < 4; ++j) {
        const int col = g * 32 + cg * 4 + j;
        const float4 f4 = *(const float4*)&s_fold[col * 4];
        const float a = acc[g][j];
        p0 = fmaf(a, f4.x, p0); p1 = fmaf(a, f4.y, p1);
        p2 = fmaf(a, f4.z, p2); p3 = fmaf(a, f4.w, p3);
      }
    }
    for (int m = 1; m < 8; m <<= 1) {
      p0 += __shfl_xor(p0, m); p1 += __shfl_xor(p1, m);
      p2 += __shfl_xor(p2, m); p3 += __shfl_xor(p3, m);
    }
    if (cg == 0) *(float4*)(aD + (size_t)gr * 4) = make_float4(p0, p1, p2, p3);
  }
}

// ---------- weight prep: frag-linear bf16 B for MFMA (+ fold columns) ----------
// Bfrag[i], i = ((t*4+ks)*64+lane)*8+j  ->  Wx[k=ks*32+(lane>>4)*8+j][n=t*16+(lane&15)]
// Wx cols: 0-127 = W; 128-131 = foldS; 132-135 = foldD; rest 0.  Set 2: Wout, 8 tiles.
__global__ __launch_bounds__(256) void prep_bfrag_kernel(
    const float* __restrict__ Wsd, const float* __restrict__ AsSd, const float* __restrict__ AdSd,
    const float* __restrict__ Wds, const float* __restrict__ AsDs, const float* __restrict__ AdDs,
    const float* __restrict__ Wout, u16* __restrict__ bf_sd, u16* __restrict__ bf_ds,
    u16* __restrict__ bf_out)
{
  __shared__ float fS[512], fD[512];
  const int b = blockIdx.x;
  const float* W = (b == 0) ? Wsd : (b == 1) ? Wds : Wout;
  const float* As = (b == 0) ? AsSd : AsDs;
  const float* Ad = (b == 0) ? AdSd : AdDs;
  u16* out = (b == 0) ? bf_sd : (b == 1) ? bf_ds : bf_out;
  const int tiles = (b == 2) ? 8 : 9;
  const int tid = threadIdx.x;
  if (b < 2) {
    if (tid < 128) {
      for (int h = 0; h < 4; ++h) {
        float s1 = 0.f, s2 = 0.f;
        for (int c = 0; c < 32; ++c) {
          const float wv = W[tid * 128 + h * 32 + c];
          s1 = fmaf(wv, As[h * 32 + c], s1);
          s2 = fmaf(wv, Ad[h * 32 + c], s2);
        }
        fS[tid * 4 + h] = s1; fD[tid * 4 + h] = s2;
      }
    }
    __syncthreads();
  }
  const int total = tiles * 4 * 64 * 8;
  for (int i = tid; i < total; i += 256) {
    const int j = i & 7, lane = (i >> 3) & 63, ks = (i >> 9) & 3, t = i >> 11;
    const int k = ks * 32 + (lane >> 4) * 8 + j;
    const int n = t * 16 + (lane & 15);
    float v;
    if (n < 128) v = W[k * 128 + n];
    else if (n < 132) v = fS[k * 4 + (n - 128)];
    else if (n < 136) v = fD[k * 4 + (n - 132)];
    else v = 0.f;
    out[i] = f2bf(v);
  }
}

// ---------- MFMA GEMM, N=144 (9 tiles): features bf16 + aS/aD logits ----------
__global__ __launch_bounds__(256) void mfma_logits_kernel(
    const short* __restrict__ A, const short* __restrict__ B,
    u16* __restrict__ outb, float* __restrict__ aS, float* __restrict__ aD, int M)
{
  __shared__ __align__(16) float lds[4][16][148];
  const int wv = threadIdx.x >> 6, lane = threadIdx.x & 63;
  const int quad = lane >> 4, l16 = lane & 15;
  const int row0 = blockIdx.x * 64 + wv * 16;
  const int arow = min(row0 + l16, M - 1);
  const short* ap = A + (size_t)arow * 128 + quad * 8;
  bf16x8 af[4];
  for (int ks = 0; ks < 4; ++ks) af[ks] = *(const bf16x8*)(ap + ks * 32);
  f32x4 acc[9];
  for (int t = 0; t < 9; ++t) acc[t] = (f32x4){0.f, 0.f, 0.f, 0.f};
  for (int ks = 0; ks < 4; ++ks)
    for (int t = 0; t < 9; ++t) {
      const bf16x8 bf = *(const bf16x8*)(B + ((t * 4 + ks) * 64 + lane) * 8);
      acc[t] = __builtin_amdgcn_mfma_f32_16x16x32_bf16(af[ks], bf, acc[t], 0, 0, 0);
    }
  for (int t = 0; t < 9; ++t)
    for (int r = 0; r < 4; ++r)
      lds[wv][quad * 4 + r][t * 16 + l16] = acc[t][r];
  __syncthreads();
  const int row = row0 + l16;
  if (row < M) {
    for (int g = 0; g < 8; ++g) {
      const f32x4 v = *(const f32x4*)&lds[wv][l16][g * 16 + quad * 4];
      uint2 pk;
      pk.x = (u32)f2bf(v[0]) | ((u32)f2bf(v[1]) << 16);
      pk.y = (u32)f2bf(v[2]) | ((u32)f2bf(v[3]) << 16);
      *(uint2*)(outb + (size_t)row * 128 + g * 16 + quad * 4) = pk;
    }
  }
  const int idx = lane & 7, rr = lane >> 3;
  for (int p = 0; p < 2; ++p) {
    const int lr = p * 8 + rr;
    const int n = row0 + lr;
    if (n < M) {
      const float v = lds[wv][lr][128 + idx];
      if (idx < 4) aS[(size_t)n * 4 + idx] = v;
      else aD[(size_t)n * 4 + idx - 4] = v;
    }
  }
}

// ---------- MFMA GEMM, N=128 (8 tiles) + bias -> fp32 out ----------
__global__ __launch_bounds__(256) void mfma_out_kernel(
    const short* __restrict__ A, const short* __restrict__ B,
    const float* __restrict__ bias, float* __restrict__ out, int M)
{
  __shared__ __align__(16) float lds[4][16][132];
  const int wv = threadIdx.x >> 6, lane = threadIdx.x & 63;
  const int quad = lane >> 4, l16 = lane & 15;
  const int row0 = blockIdx.x * 64 + wv * 16;
  const int arow = min(row0 + l16, M - 1);
  const short* ap = A + (size_t)arow * 128 + quad * 8;
  bf16x8 af[4];
  for (int ks = 0; ks < 4; ++ks) af[ks] = *(const bf16x8*)(ap + ks * 32);
  f32x4 acc[8];
  for (int t = 0; t < 8; ++t) acc[t] = (f32x4){0.f, 0.f, 0.f, 0.f};
  for (int ks = 0; ks < 4; ++ks)
    for (int t = 0; t < 8; ++t) {
      const bf16x8 bf = *(const bf16x8*)(B + ((t * 4 + ks) * 64 + lane) * 8);
      acc[t] = __builtin_amdgcn_mfma_f32_16x16x32_bf16(af[ks], bf, acc[t], 0, 0, 0);
    }
  for (int t = 0; t < 8; ++t)
    for (int r = 0; r < 4; ++r)
      lds[wv][quad * 4 + r][t * 16 + l16] = acc[t][r];
  __syncthreads();
  const int row = row0 + l16;
  if (row < M) {
    for (int g = 0; g < 8; ++g) {
      const int col = g * 16 + quad * 4;
      f32x4 v = *(const f32x4*)&lds[wv][l16][col];
      const f32x4 b4 = *(const f32x4*)(bias + col);
      v = v + b4;
      *(f32x4*)(out + (size_t)row * 128 + col) = v;
    }
  }
}

// ---------- K4: hcs = relu(x_c @ Wpc + b) @ Wcs (bf16) + a_s_ct ----------
__global__ __launch_bounds__(256) void ctx_kernel(const float* __restrict__ x_c,
    const float* __restrict__ Wpc, const float* __restrict__ bpc,
    const float* __restrict__ Wcs, const float* __restrict__ attS,
    u16* __restrict__ hc_bf, float* __restrict__ aS, int N)
{
  __shared__ float s_in[32][33];
  __shared__ float s_W[32][128];
  __shared__ float s_h[32][132];
  const int t = threadIdx.x;
  const int row0 = blockIdx.x * 32;
  const int rl = t >> 3, cg = t & 7;
  const int gr = row0 + rl;
  {
    float4 f = make_float4(0.f, 0.f, 0.f, 0.f);
    if (gr < N) f = *(const float4*)(x_c + (size_t)gr * 32 + cg * 4);
    s_in[rl][cg * 4 + 0] = f.x; s_in[rl][cg * 4 + 1] = f.y;
    s_in[rl][cg * 4 + 2] = f.z; s_in[rl][cg * 4 + 3] = f.w;
  }
  for (int j = 0; j < 4; ++j) {
    const int idx = t + j * 256;
    const int k = idx >> 5, c4 = (idx & 31) * 4;
    *(float4*)&s_W[k][c4] = *(const float4*)(Wpc + (size_t)k * 128 + c4);
  }
  __syncthreads();
  float acc[4][4];
  for (int g = 0; g < 4; ++g)
    for (int j = 0; j < 4; ++j) acc[g][j] = bpc[g * 32 + cg * 4 + j];
#pragma unroll 8
  for (int k = 0; k < 32; ++k) {
    const float a = s_in[rl][k];
    for (int g = 0; g < 4; ++g) {
      const float4 w = *(const float4*)&s_W[k][g * 32 + cg * 4];
      acc[g][0] = fmaf(a, w.x, acc[g][0]);
      acc[g][1] = fmaf(a, w.y, acc[g][1]);
      acc[g][2] = fmaf(a, w.z, acc[g][2]);
      acc[g][3] = fmaf(a, w.w, acc[g][3]);
    }
  }
  for (int g = 0; g < 4; ++g)
    *(float4*)&s_h[rl][g * 32 + cg * 4] =
        make_float4(fmaxf(acc[g][0], 0.f), fmaxf(acc[g][1], 0.f),
                    fmaxf(acc[g][2], 0.f), fmaxf(acc[g][3], 0.f));
  __syncthreads();
  float acc2[4][4];
  for (int g = 0; g < 4; ++g)
    for (int j = 0; j < 4; ++j) acc2[g][j] = 0.f;
  for (int kc = 0; kc < 128; kc += 32) {
    for (int j = 0; j < 4; ++j) {
      const int idx = t + j * 256;
      const int k = idx >> 5, c4 = (idx & 31) * 4;
      *(float4*)&s_W[k][c4] = *(const float4*)(Wcs + (size_t)(kc + k) * 128 + c4);
    }
    __syncthreads();
#pragma unroll 8
    for (int k = 0; k < 32; ++k) {
      const float a = s_h[rl][kc + k];
      for (int g = 0; g < 4; ++g) {
        const float4 w = *(const float4*)&s_W[k][g * 32 + cg * 4];
        acc2[g][0] = fmaf(a, w.x, acc2[g][0]);
        acc2[g][1] = fmaf(a, w.y, acc2[g][1]);
        acc2[g][2] = fmaf(a, w.z, acc2[g][2]);
        acc2[g][3] = fmaf(a, w.w, acc2[g][3]);
      }
    }
    __syncthreads();
  }
  if (gr < N) {
    float pS[4];
    for (int g = 0; g < 4; ++g) {
      uint2 pk;
      pk.x = (u32)f2bf(acc2[g][0]) | ((u32)f2bf(acc2[g][1]) << 16);
      pk.y = (u32)f2bf(acc2[g][2]) | ((u32)f2bf(acc2[g][3]) << 16);
      *(uint2*)(hc_bf + (size_t)gr * 128 + g * 32 + cg * 4) = pk;
      const float4 as4 = *(const float4*)(attS + g * 32 + cg * 4);
      pS[g] = acc2[g][0] * as4.x + acc2[g][1] * as4.y + acc2[g][2] * as4.z + acc2[g][3] * as4.w;
    }
    for (int m = 1; m < 8; m <<= 1)
      for (int g = 0; g < 4; ++g) pS[g] += __shfl_xor(pS[g], m);
    if (cg == 0)
      *(float4*)(aS + (size_t)gr * 4) = make_float4(pS[0], pS[1], pS[2], pS[3]);
  }
}

// ---------- fold_cd + combined bias ----------
__global__ void fold_all_kernel(const float* __restrict__ Wcd, const float* __restrict__ attD,
    const float* __restrict__ bsd, const float* __restrict__ bds, const float* __restrict__ bct,
    float* __restrict__ fold_cd, float* __restrict__ cbias)
{
  const int k = threadIdx.x;  // 128
  if (blockIdx.x == 0) {
    for (int h = 0; h < 4; ++h) {
      float s = 0.f;
      for (int c = 0; c < 32; ++c)
        s = fmaf(Wcd[k * 128 + h * 32 + c], attD[h * 32 + c], s);
      fold_cd[k * 4 + h] = s;
    }
  } else {
    cbias[k] = 0.25f * bsd[k] + 0.25f * bds[k] + 0.5f * bct[k];
  }
}

// ---------- CSR build ----------
__global__ void hist_all_kernel(const int* __restrict__ tt_src, const int* __restrict__ tt_dst,
    const int* __restrict__ ect_d, int* __restrict__ cnt_f, int* __restrict__ cnt_r,
    int* __restrict__ cnt_c)
{
  const int e = blockIdx.x * blockDim.x + threadIdx.x;
  if (e < ETT) {
    atomicAdd(&cnt_f[tt_dst[e]], 1);
    atomicAdd(&cnt_r[tt_src[e]], 1);
  }
  if (e < ECT) atomicAdd(&cnt_c[ect_d[e]], 1);
}

__global__ __launch_bounds__(256) void scan_blk_kernel(const int* __restrict__ cnt,
    int* __restrict__ off, int* __restrict__ bsum)
{
  const int a = blockIdx.x / NB_PER;
  const int b = blockIdx.x % NB_PER;
  const int t = threadIdx.x;
  const int* c = cnt + (size_t)a * NT;
  int* o = off + (size_t)a * OFFS;
  const int idx = b * 2048 + t * 8;
  int v[8];
  int s = 0;
  if (idx < NT) {
    const int4 q0 = *(const int4*)(c + idx);
    const int4 q1 = *(const int4*)(c + idx + 4);
    int x;
    x = q0.x; v[0] = s; s += x;  x = q0.y; v[1] = s; s += x;
    x = q0.z; v[2] = s; s += x;  x = q0.w; v[3] = s; s += x;
    x = q1.x; v[4] = s; s += x;  x = q1.y; v[5] = s; s += x;
    x = q1.z; v[6] = s; s += x;  x = q1.w; v[7] = s; s += x;
  } else {
    for (int j = 0; j < 8; ++j) v[j] = 0;
  }
  __shared__ int sh[256];
  sh[t] = s;
  __syncthreads();
  for (int d = 1; d < 256; d <<= 1) {
    const int u = (t >= d) ? sh[t - d] : 0;
    __syncthreads();
    sh[t] += u;
    __syncthreads();
  }
  const int excl = (t == 0) ? 0 : sh[t - 1];
  if (idx < NT) {
    int4 q0, q1;
    q0.x = excl + v[0]; q0.y = excl + v[1]; q0.z = excl + v[2]; q0.w = excl + v[3];
    q1.x = excl + v[4]; q1.y = excl + v[5]; q1.z = excl + v[6]; q1.w = excl + v[7];
    *(int4*)(o + idx) = q0;
    *(int4*)(o + idx + 4) = q1;
  }
  if (t == 255) bsum[blockIdx.x] = sh[255];
}

__global__ __launch_bounds__(192) void scan_top_kernel(const int* __restrict__ bsum,
    int* __restrict__ bpre, int* __restrict__ off)
{
  const int t = threadIdx.x;
  const int w = t >> 6, lane = t & 63;
  if (w >= 3) return;
  const int orig = (lane < NB_PER) ? bsum[w * NB_PER + lane] : 0;
  int v = orig;
  for (int d = 1; d < 64; d <<= 1) {
    const int u = __shfl_up(v, d);
    if (lane >= d) v += u;
  }
  if (lane < NB_PER) bpre[w * NB_PER + lane] = v - orig;
  if (lane == NB_PER - 1) off[(size_t)w * OFFS + NT] = v;
}

__global__ __launch_bounds__(256) void scan_add_kernel(const int* __restrict__ bpre,
    int* __restrict__ off, int* __restrict__ cur)
{
  const int a = blockIdx.x / NB_PER;
  const int b = blockIdx.x % NB_PER;
  const int t = threadIdx.x;
  const int bp = bpre[blockIdx.x];
  int* o = off + (size_t)a * OFFS;
  int* cu = cur + (size_t)a * NT;
  const int idx = b * 2048 + t * 8;
  if (idx < NT) {
    int4 q0 = *(const int4*)(o + idx);
    int4 q1 = *(const int4*)(o + idx + 4);
    q0.x += bp; q0.y += bp; q0.z += bp; q0.w += bp;
    q1.x += bp; q1.y += bp; q1.z += bp; q1.w += bp;
    *(int4*)(o + idx) = q0;     *(int4*)(o + idx + 4) = q1;
    *(int4*)(cu + idx) = q0;    *(int4*)(cu + idx + 4) = q1;
  }
}

__global__ void fill_all_kernel(const int* __restrict__ tt_src, const int* __restrict__ tt_dst,
    const int* __restrict__ ect_s, const int* __restrict__ ect_d,
    int* __restrict__ cur_f, int* __restrict__ cur_r, int* __restrict__ cur_c,
    int* __restrict__ el_f, int* __restrict__ el_r, int* __restrict__ el_c)
{
  const int e = blockIdx.x * blockDim.x + threadIdx.x;
  if (e < ETT) {
    const int s = tt_src[e], d = tt_dst[e];
    el_f[atomicAdd(&cur_f[d], 1)] = s;
    el_r[atomicAdd(&cur_r[s], 1)] = d;
  }
  if (e < ECT)
    el_c[atomicAdd(&cur_c[ect_d[e]], 1)] = ect_s[e];
}

// ---------- K5: fused 3-relation gather, software-pipelined (depth 2) ----------
__device__ __forceinline__ void gat_pipe(const int* __restrict__ off,
    const int* __restrict__ el, const float* __restrict__ aS, const float* __restrict__ aD,
    const u16* __restrict__ hb, int d, int h, int c0, int self_loop, float w,
    float& x0, float& x1)
{
  const float ad = aD[(size_t)d * 4 + h];
  const int beg = off[d];
  const int m = off[d + 1] - beg;     // real edges
  const int cnt = m + self_loop;
  if (cnt <= 0) return;
  float den = 0.f, a0 = 0.f, a1 = 0.f;
  int s_a = (0 < m) ? el[beg] : d;
  int s_b = (1 < m) ? el[beg + 1] : d;
  float e_a = aS[(size_t)s_a * 4 + h];
  u32 p_a = *(const u32*)(hb + (size_t)s_a * 128 + c0);
  for (int k = 0; k < cnt; ++k) {
    const int s_c = (k + 2 < m) ? el[beg + k + 2] : d;
    const float e_b = aS[(size_t)s_b * 4 + h];
    const u32 p_b = *(const u32*)(hb + (size_t)s_b * 128 + c0);
    float ea = e_a + ad;
    ea = ea > 0.f ? ea : SLOPE * ea;
    const float ex = __expf(ea);
    den += ex;
    a0 = fmaf(ex, lof(p_a), a0);
    a1 = fmaf(ex, hif(p_a), a1);
    e_a = e_b; p_a = p_b; s_b = s_c;
  }
  const float inv = den > 0.f ? w / den : 0.f;
  x0 = fmaf(a0, inv, x0);
  x1 = fmaf(a1, inv, x1);
}

__global__ __launch_bounds__(256) void gather_all_kernel(
    const int* __restrict__ off_f, const int* __restrict__ el_f,
    const float* __restrict__ aS_sd, const float* __restrict__ aD_sd, const u16* __restrict__ hs,
    const int* __restrict__ off_r, const int* __restrict__ el_r,
    const float* __restrict__ aS_ds, const float* __restrict__ aD_ds, const u16* __restrict__ hd,
    const int* __restrict__ off_c, const int* __restrict__ el_c,
    const float* __restrict__ aS_ct, const float* __restrict__ aD_ct, const u16* __restrict__ hc,
    const u16* __restrict__ skip, const float* __restrict__ cbias, u16* __restrict__ x)
{
  const int d = blockIdx.x * 4 + (threadIdx.x >> 6);
  if (d >= NT) return;
  const int lane = threadIdx.x & 63;
  const int h = lane >> 4;
  const int c0 = lane * 2;
  float x0 = 0.f, x1 = 0.f;
  gat_pipe(off_f, el_f, aS_sd, aD_sd, hs, d, h, c0, 1, 0.25f, x0, x1);
  gat_pipe(off_r, el_r, aS_ds, aD_ds, hd, d, h, c0, 1, 0.25f, x0, x1);
  gat_pipe(off_c, el_c, aS_ct, aD_ct, hc, d, h, c0, 0, 0.5f, x0, x1);
  const u32 sk = *(const u32*)(skip + (size_t)d * 128 + c0);
  const float2 cb = *(const float2*)(cbias + c0);
  const float o0 = fmaxf(x0 + cb.x + lof(sk), 0.f);
  const float o1 = fmaxf(x1 + cb.y + hif(sk), 0.f);
  *(u32*)(x + (size_t)d * 128 + c0) = (u32)f2bf(o0) | ((u32)f2bf(o1) << 16);
}

extern "C" void kernel_launch(void* const* d_in, const int* in_sizes, int n_in,
                              void* d_out, int out_size, void* d_ws, size_t ws_size,
                              hipStream_t stream)
{
  const float* x_t   = (const float*)d_in[0];
  const float* x_c   = (const float*)d_in[1];
  const int*   e_tt  = (const int*)d_in[2];
  const int*   ect_s = (const int*)d_in[3];
  const int*   ect_d = (const int*)d_in[4];
  const float* Wpt = (const float*)d_in[5];   const float* bpt = (const float*)d_in[6];
  const float* Wpc = (const float*)d_in[7];   const float* bpc = (const float*)d_in[8];
  const float* Wsd = (const float*)d_in[9];   const float* As_sd = (const float*)d_in[10];
  const float* Ad_sd = (const float*)d_in[11]; const float* bsd = (const float*)d_in[12];
  const float* Wds = (const float*)d_in[13];  const float* As_ds = (const float*)d_in[14];
  const float* Ad_ds = (const float*)d_in[15]; const float* bds = (const float*)d_in[16];
  const float* Wcs = (const float*)d_in[17];  const float* Wcd = (const float*)d_in[18];
  const float* As_ct = (const float*)d_in[19]; const float* Ad_ct = (const float*)d_in[20];
  const float* bct = (const float*)d_in[21];
  const float* Wout = (const float*)d_in[22]; const float* bout = (const float*)d_in[23];

  // workspace (~130 MB)
  char* p = (char*)d_ws;
  size_t off = 0;
  auto alloc = [&](size_t bytes) { char* r = p + off; off += (bytes + 255) & ~(size_t)255; return r; };
  u16* ht_bf   = (u16*)alloc((size_t)NT * 128 * 2);
  u16* hs_bf   = (u16*)alloc((size_t)NT * 128 * 2);
  u16* hd_bf   = (u16*)alloc((size_t)NT * 128 * 2);
  u16* hc_bf   = (u16*)alloc((size_t)NC * 128 * 2);
  u16* x_bf    = (u16*)alloc((size_t)NT * 128 * 2);
  float* aS_sd = (float*)alloc((size_t)NT * 4 * 4);
  float* aD_sd = (float*)alloc((size_t)NT * 4 * 4);
  float* aS_ds = (float*)alloc((size_t)NT * 4 * 4);
  float* aD_ds = (float*)alloc((size_t)NT * 4 * 4);
  float* aS_ct = (float*)alloc((size_t)NC * 4 * 4);
  float* aD_ct = (float*)alloc((size_t)NT * 4 * 4);
  int* cnt  = (int*)alloc((size_t)3 * NT * 4);          // reused as cur after scan
  int* offs = (int*)alloc((size_t)3 * OFFS * 4);
  int* el_f = (int*)alloc((size_t)ETT * 4);
  int* el_r = (int*)alloc((size_t)ETT * 4);
  int* el_c = (int*)alloc((size_t)ECT * 4);
  int* bsum = (int*)alloc((size_t)3 * NB_PER * 4);
  int* bpre = (int*)alloc((size_t)3 * NB_PER * 4);
  float* fold_cd = (float*)alloc(512 * 4);
  float* cbias   = (float*)alloc(128 * 4);
  u16* bfrag_sd  = (u16*)alloc((size_t)9 * 4 * 64 * 8 * 2);
  u16* bfrag_ds  = (u16*)alloc((size_t)9 * 4 * 64 * 8 * 2);
  u16* bfrag_out = (u16*)alloc((size_t)8 * 4 * 64 * 8 * 2);

  int* cnt_f = cnt;          int* cnt_r = cnt + NT;         int* cnt_c = cnt + 2 * NT;
  int* off_f = offs;         int* off_r = offs + OFFS;      int* off_c = offs + 2 * OFFS;

  const int* tt_src = e_tt;
  const int* tt_dst = e_tt + ETT;

  const int gT = (NT + 31) / 32;       // 3125
  const int gC = (NC + 31) / 32;       // 782
  const int gE = (ETT + 255) / 256;
  const int gM = (NT + 63) / 64;       // 1563 (MFMA blocks)

  // CSR build
  hipMemsetAsync(cnt, 0, (size_t)3 * NT * 4, stream);
  hist_all_kernel<<<gE, 256, 0, stream>>>(tt_src, tt_dst, ect_d, cnt_f, cnt_r, cnt_c);
  scan_blk_kernel<<<3 * NB_PER, 256, 0, stream>>>(cnt, offs, bsum);
  scan_top_kernel<<<1, 192, 0, stream>>>(bsum, bpre, offs);
  scan_add_kernel<<<3 * NB_PER, 256, 0, stream>>>(bpre, offs, cnt);
  fill_all_kernel<<<gE, 256, 0, stream>>>(tt_src, tt_dst, ect_s, ect_d,
                                          cnt_f, cnt_r, cnt_c, el_f, el_r, el_c);

  // weight prep: MFMA frag layouts + fold_cd + cbias
  prep_bfrag_kernel<<<3, 256, 0, stream>>>(Wsd, As_sd, Ad_sd, Wds, As_ds, Ad_ds, Wout,
                                           bfrag_sd, bfrag_ds, bfrag_out);
  fold_all_kernel<<<2, 128, 0, stream>>>(Wcd, Ad_ct, bsd, bds, bct, fold_cd, cbias);

  // node transforms
  pre_t_kernel<<<gT, 256, 0, stream>>>(x_t, Wpt, bpt, fold_cd, ht_bf, aD_ct, NT);
  mfma_logits_kernel<<<gM, 256, 0, stream>>>((const short*)ht_bf, (const short*)bfrag_sd,
                                             hs_bf, aS_sd, aD_sd, NT);
  mfma_logits_kernel<<<gM, 256, 0, stream>>>((const short*)ht_bf, (const short*)bfrag_ds,
                                             hd_bf, aS_ds, aD_ds, NT);
  ctx_kernel<<<gC, 256, 0, stream>>>(x_c, Wpc, bpc, Wcs, As_ct, hc_bf, aS_ct, NC);

  // fused gather (sd + ds + ct + cbias + skip + relu) -> x_bf
  gather_all_kernel<<<(NT + 3) / 4, 256, 0, stream>>>(
      off_f, el_f, aS_sd, aD_sd, hs_bf,
      off_r, el_r, aS_ds, aD_ds, hd_bf,
      off_c, el_c, aS_ct, aD_ct, hc_bf,
      ht_bf, cbias, x_bf);

  // final MFMA GEMM -> d_out (fp32)
  mfma_out_kernel<<<gM, 256, 0, stream>>>((const short*)x_bf, (const short*)bfrag_out,
                                          bout, (float*)d_out, NT);
}

// Round 6
// 511.491 us; speedup vs baseline: 8.5238x; 1.3647x over previous
//
#include <hip/hip_runtime.h>
#include <cstdint>
#include <cstddef>

typedef unsigned short u16;
typedef unsigned int u32;

#define NT 100000
#define NC 25000
#define ETT 800000
#define ECT 400000
#define SLOPE 0.2f
#define OFFS (NT + 4)           // padded stride for offset arrays (16B-aligned)

// bucket-binned CSR build
#define NBK 782                 // ceil(NT/128) buckets of 128 nodes
#define NBLK 256                // binning blocks
#define CHT ((ETT + NBLK - 1) / NBLK)   // 3125 tt edges / block
#define CHC ((ECT + NBLK - 1) / NBLK)   // 1563 ct edges / block
#define TOTC (3 * NBK * NBLK)           // 600576 counts
#define NSB ((TOTC + 2047) / 2048)      // 294 scan blocks

typedef __attribute__((ext_vector_type(8))) short bf16x8;
typedef __attribute__((ext_vector_type(4))) float f32x4;

__device__ __forceinline__ u16 f2bf(float f) {
  u32 u = __float_as_uint(f);
  u32 r = (u >> 16) & 1u;
  return (u16)((u + 0x7fffu + r) >> 16);
}
__device__ __forceinline__ float lof(u32 p) { return __uint_as_float(p << 16); }
__device__ __forceinline__ float hif(u32 p) { return __uint_as_float(p & 0xffff0000u); }

// ---------- K1: h_t(bf16) = relu(x_t @ Wpt + b); aD_ct = relu(h_t) @ fold_cd ----------
__global__ __launch_bounds__(256) void pre_t_kernel(const float* __restrict__ in,
    const float* __restrict__ W, const float* __restrict__ bias,
    const float* __restrict__ fold_cd, u16* __restrict__ h_t,
    float* __restrict__ aD, int N)
{
  __shared__ float s_in[32][33];
  __shared__ float s_W[32][128];
  __shared__ float s_fold[512];
  const int t = threadIdx.x;
  s_fold[t] = fold_cd[t];
  s_fold[t + 256] = fold_cd[t + 256];
  const int row0 = blockIdx.x * 32;
  const int rl = t >> 3, cg = t & 7;
  const int gr = row0 + rl;
  float acc[4][4];
  for (int g = 0; g < 4; ++g)
    for (int j = 0; j < 4; ++j)
      acc[g][j] = bias[g * 32 + cg * 4 + j];
  for (int kc = 0; kc < 64; kc += 32) {
    {
      float4 f = make_float4(0.f, 0.f, 0.f, 0.f);
      if (gr < N) f = *(const float4*)(in + (size_t)gr * 64 + kc + cg * 4);
      s_in[rl][cg * 4 + 0] = f.x; s_in[rl][cg * 4 + 1] = f.y;
      s_in[rl][cg * 4 + 2] = f.z; s_in[rl][cg * 4 + 3] = f.w;
    }
    for (int j = 0; j < 4; ++j) {
      const int idx = t + j * 256;
      const int k = idx >> 5, c4 = (idx & 31) * 4;
      *(float4*)&s_W[k][c4] = *(const float4*)(W + (size_t)(kc + k) * 128 + c4);
    }
    __syncthreads();
#pragma unroll 8
    for (int k = 0; k < 32; ++k) {
      const float a = s_in[rl][k];
      for (int g = 0; g < 4; ++g) {
        const float4 w = *(const float4*)&s_W[k][g * 32 + cg * 4];
        acc[g][0] = fmaf(a, w.x, acc[g][0]);
        acc[g][1] = fmaf(a, w.y, acc[g][1]);
        acc[g][2] = fmaf(a, w.z, acc[g][2]);
        acc[g][3] = fmaf(a, w.w, acc[g][3]);
      }
    }
    __syncthreads();
  }
  if (gr < N) {
    float p0 = 0.f, p1 = 0.f, p2 = 0.f, p3 = 0.f;
    for (int g = 0; g < 4; ++g) {
      for (int j = 0; j < 4; ++j) acc[g][j] = fmaxf(acc[g][j], 0.f);
      uint2 pk;
      pk.x = (u32)f2bf(acc[g][0]) | ((u32)f2bf(acc[g][1]) << 16);
      pk.y = (u32)f2bf(acc[g][2]) | ((u32)f2bf(acc[g][3]) << 16);
      *(uint2*)(h_t + (size_t)gr * 128 + g * 32 + cg * 4) = pk;
      for (int j = 0; j < 4; ++j) {
        const int col = g * 32 + cg * 4 + j;
        const float4 f4 = *(const float4*)&s_fold[col * 4];
        const float a = acc[g][j];
        p0 = fmaf(a, f4.x, p0); p1 = fmaf(a, f4.y, p1);
        p2 = fmaf(a, f4.z, p2); p3 = fmaf(a, f4.w, p3);
      }
    }
    for (int m = 1; m < 8; m <<= 1) {
      p0 += __shfl_xor(p0, m); p1 += __shfl_xor(p1, m);
      p2 += __shfl_xor(p2, m); p3 += __shfl_xor(p3, m);
    }
    if (cg == 0) *(float4*)(aD + (size_t)gr * 4) = make_float4(p0, p1, p2, p3);
  }
}

// ---------- weight prep: frag-linear bf16 B for MFMA (+ fold columns) ----------
__global__ __launch_bounds__(256) void prep_bfrag_kernel(
    const float* __restrict__ Wsd, const float* __restrict__ AsSd, const float* __restrict__ AdSd,
    const float* __restrict__ Wds, const float* __restrict__ AsDs, const float* __restrict__ AdDs,
    const float* __restrict__ Wout, u16* __restrict__ bf_sd, u16* __restrict__ bf_ds,
    u16* __restrict__ bf_out)
{
  __shared__ float fS[512], fD[512];
  const int b = blockIdx.x;
  const float* W = (b == 0) ? Wsd : (b == 1) ? Wds : Wout;
  const float* As = (b == 0) ? AsSd : AsDs;
  const float* Ad = (b == 0) ? AdSd : AdDs;
  u16* out = (b == 0) ? bf_sd : (b == 1) ? bf_ds : bf_out;
  const int tiles = (b == 2) ? 8 : 9;
  const int tid = threadIdx.x;
  if (b < 2) {
    if (tid < 128) {
      for (int h = 0; h < 4; ++h) {
        float s1 = 0.f, s2 = 0.f;
        for (int c = 0; c < 32; ++c) {
          const float wv = W[tid * 128 + h * 32 + c];
          s1 = fmaf(wv, As[h * 32 + c], s1);
          s2 = fmaf(wv, Ad[h * 32 + c], s2);
        }
        fS[tid * 4 + h] = s1; fD[tid * 4 + h] = s2;
      }
    }
    __syncthreads();
  }
  const int total = tiles * 4 * 64 * 8;
  for (int i = tid; i < total; i += 256) {
    const int j = i & 7, lane = (i >> 3) & 63, ks = (i >> 9) & 3, t = i >> 11;
    const int k = ks * 32 + (lane >> 4) * 8 + j;
    const int n = t * 16 + (lane & 15);
    float v;
    if (n < 128) v = W[k * 128 + n];
    else if (n < 132) v = fS[k * 4 + (n - 128)];
    else if (n < 136) v = fD[k * 4 + (n - 132)];
    else v = 0.f;
    out[i] = f2bf(v);
  }
}

// ---------- MFMA GEMM, N=144 (9 tiles): features bf16 + aS/aD logits ----------
__global__ __launch_bounds__(256) void mfma_logits_kernel(
    const short* __restrict__ A, const short* __restrict__ B,
    u16* __restrict__ outb, float* __restrict__ aS, float* __restrict__ aD, int M)
{
  __shared__ __align__(16) float lds[4][16][148];
  const int wv = threadIdx.x >> 6, lane = threadIdx.x & 63;
  const int quad = lane >> 4, l16 = lane & 15;
  const int row0 = blockIdx.x * 64 + wv * 16;
  const int arow = min(row0 + l16, M - 1);
  const short* ap = A + (size_t)arow * 128 + quad * 8;
  bf16x8 af[4];
  for (int ks = 0; ks < 4; ++ks) af[ks] = *(const bf16x8*)(ap + ks * 32);
  f32x4 acc[9];
  for (int t = 0; t < 9; ++t) acc[t] = (f32x4){0.f, 0.f, 0.f, 0.f};
  for (int ks = 0; ks < 4; ++ks)
    for (int t = 0; t < 9; ++t) {
      const bf16x8 bf = *(const bf16x8*)(B + ((t * 4 + ks) * 64 + lane) * 8);
      acc[t] = __builtin_amdgcn_mfma_f32_16x16x32_bf16(af[ks], bf, acc[t], 0, 0, 0);
    }
  for (int t = 0; t < 9; ++t)
    for (int r = 0; r < 4; ++r)
      lds[wv][quad * 4 + r][t * 16 + l16] = acc[t][r];
  __syncthreads();
  const int row = row0 + l16;
  if (row < M) {
    for (int g = 0; g < 8; ++g) {
      const f32x4 v = *(const f32x4*)&lds[wv][l16][g * 16 + quad * 4];
      uint2 pk;
      pk.x = (u32)f2bf(v[0]) | ((u32)f2bf(v[1]) << 16);
      pk.y = (u32)f2bf(v[2]) | ((u32)f2bf(v[3]) << 16);
      *(uint2*)(outb + (size_t)row * 128 + g * 16 + quad * 4) = pk;
    }
  }
  const int idx = lane & 7, rr = lane >> 3;
  for (int p = 0; p < 2; ++p) {
    const int lr = p * 8 + rr;
    const int n = row0 + lr;
    if (n < M) {
      const float v = lds[wv][lr][128 + idx];
      if (idx < 4) aS[(size_t)n * 4 + idx] = v;
      else aD[(size_t)n * 4 + idx - 4] = v;
    }
  }
}

// ---------- MFMA GEMM, N=128 (8 tiles) + bias -> fp32 out ----------
__global__ __launch_bounds__(256) void mfma_out_kernel(
    const short* __restrict__ A, const short* __restrict__ B,
    const float* __restrict__ bias, float* __restrict__ out, int M)
{
  __shared__ __align__(16) float lds[4][16][132];
  const int wv = threadIdx.x >> 6, lane = threadIdx.x & 63;
  const int quad = lane >> 4, l16 = lane & 15;
  const int row0 = blockIdx.x * 64 + wv * 16;
  const int arow = min(row0 + l16, M - 1);
  const short* ap = A + (size_t)arow * 128 + quad * 8;
  bf16x8 af[4];
  for (int ks = 0; ks < 4; ++ks) af[ks] = *(const bf16x8*)(ap + ks * 32);
  f32x4 acc[8];
  for (int t = 0; t < 8; ++t) acc[t] = (f32x4){0.f, 0.f, 0.f, 0.f};
  for (int ks = 0; ks < 4; ++ks)
    for (int t = 0; t < 8; ++t) {
      const bf16x8 bf = *(const bf16x8*)(B + ((t * 4 + ks) * 64 + lane) * 8);
      acc[t] = __builtin_amdgcn_mfma_f32_16x16x32_bf16(af[ks], bf, acc[t], 0, 0, 0);
    }
  for (int t = 0; t < 8; ++t)
    for (int r = 0; r < 4; ++r)
      lds[wv][quad * 4 + r][t * 16 + l16] = acc[t][r];
  __syncthreads();
  const int row = row0 + l16;
  if (row < M) {
    for (int g = 0; g < 8; ++g) {
      const int col = g * 16 + quad * 4;
      f32x4 v = *(const f32x4*)&lds[wv][l16][col];
      const f32x4 b4 = *(const f32x4*)(bias + col);
      v = v + b4;
      *(f32x4*)(out + (size_t)row * 128 + col) = v;
    }
  }
}

// ---------- K4: hcs = relu(x_c @ Wpc + b) @ Wcs (bf16) + a_s_ct ----------
__global__ __launch_bounds__(256) void ctx_kernel(const float* __restrict__ x_c,
    const float* __restrict__ Wpc, const float* __restrict__ bpc,
    const float* __restrict__ Wcs, const float* __restrict__ attS,
    u16* __restrict__ hc_bf, float* __restrict__ aS, int N)
{
  __shared__ float s_in[32][33];
  __shared__ float s_W[32][128];
  __shared__ float s_h[32][132];
  const int t = threadIdx.x;
  const int row0 = blockIdx.x * 32;
  const int rl = t >> 3, cg = t & 7;
  const int gr = row0 + rl;
  {
    float4 f = make_float4(0.f, 0.f, 0.f, 0.f);
    if (gr < N) f = *(const float4*)(x_c + (size_t)gr * 32 + cg * 4);
    s_in[rl][cg * 4 + 0] = f.x; s_in[rl][cg * 4 + 1] = f.y;
    s_in[rl][cg * 4 + 2] = f.z; s_in[rl][cg * 4 + 3] = f.w;
  }
  for (int j = 0; j < 4; ++j) {
    const int idx = t + j * 256;
    const int k = idx >> 5, c4 = (idx & 31) * 4;
    *(float4*)&s_W[k][c4] = *(const float4*)(Wpc + (size_t)k * 128 + c4);
  }
  __syncthreads();
  float acc[4][4];
  for (int g = 0; g < 4; ++g)
    for (int j = 0; j < 4; ++j) acc[g][j] = bpc[g * 32 + cg * 4 + j];
#pragma unroll 8
  for (int k = 0; k < 32; ++k) {
    const float a = s_in[rl][k];
    for (int g = 0; g < 4; ++g) {
      const float4 w = *(const float4*)&s_W[k][g * 32 + cg * 4];
      acc[g][0] = fmaf(a, w.x, acc[g][0]);
      acc[g][1] = fmaf(a, w.y, acc[g][1]);
      acc[g][2] = fmaf(a, w.z, acc[g][2]);
      acc[g][3] = fmaf(a, w.w, acc[g][3]);
    }
  }
  for (int g = 0; g < 4; ++g)
    *(float4*)&s_h[rl][g * 32 + cg * 4] =
        make_float4(fmaxf(acc[g][0], 0.f), fmaxf(acc[g][1], 0.f),
                    fmaxf(acc[g][2], 0.f), fmaxf(acc[g][3], 0.f));
  __syncthreads();
  float acc2[4][4];
  for (int g = 0; g < 4; ++g)
    for (int j = 0; j < 4; ++j) acc2[g][j] = 0.f;
  for (int kc = 0; kc < 128; kc += 32) {
    for (int j = 0; j < 4; ++j) {
      const int idx = t + j * 256;
      const int k = idx >> 5, c4 = (idx & 31) * 4;
      *(float4*)&s_W[k][c4] = *(const float4*)(Wcs + (size_t)(kc + k) * 128 + c4);
    }
    __syncthreads();
#pragma unroll 8
    for (int k = 0; k < 32; ++k) {
      const float a = s_h[rl][kc + k];
      for (int g = 0; g < 4; ++g) {
        const float4 w = *(const float4*)&s_W[k][g * 32 + cg * 4];
        acc2[g][0] = fmaf(a, w.x, acc2[g][0]);
        acc2[g][1] = fmaf(a, w.y, acc2[g][1]);
        acc2[g][2] = fmaf(a, w.z, acc2[g][2]);
        acc2[g][3] = fmaf(a, w.w, acc2[g][3]);
      }
    }
    __syncthreads();
  }
  if (gr < N) {
    float pS[4];
    for (int g = 0; g < 4; ++g) {
      uint2 pk;
      pk.x = (u32)f2bf(acc2[g][0]) | ((u32)f2bf(acc2[g][1]) << 16);
      pk.y = (u32)f2bf(acc2[g][2]) | ((u32)f2bf(acc2[g][3]) << 16);
      *(uint2*)(hc_bf + (size_t)gr * 128 + g * 32 + cg * 4) = pk;
      const float4 as4 = *(const float4*)(attS + g * 32 + cg * 4);
      pS[g] = acc2[g][0] * as4.x + acc2[g][1] * as4.y + acc2[g][2] * as4.z + acc2[g][3] * as4.w;
    }
    for (int m = 1; m < 8; m <<= 1)
      for (int g = 0; g < 4; ++g) pS[g] += __shfl_xor(pS[g], m);
    if (cg == 0)
      *(float4*)(aS + (size_t)gr * 4) = make_float4(pS[0], pS[1], pS[2], pS[3]);
  }
}

// ---------- fold_cd + combined bias ----------
__global__ void fold_all_kernel(const float* __restrict__ Wcd, const float* __restrict__ attD,
    const float* __restrict__ bsd, const float* __restrict__ bds, const float* __restrict__ bct,
    float* __restrict__ fold_cd, float* __restrict__ cbias)
{
  const int k = threadIdx.x;  // 128
  if (blockIdx.x == 0) {
    for (int h = 0; h < 4; ++h) {
      float s = 0.f;
      for (int c = 0; c < 32; ++c)
        s = fmaf(Wcd[k * 128 + h * 32 + c], attD[h * 32 + c], s);
      fold_cd[k * 4 + h] = s;
    }
  } else {
    cbias[k] = 0.25f * bsd[k] + 0.25f * bds[k] + 0.5f * bct[k];
  }
}

// ---------- bucket-binned CSR build (no global atomics) ----------
// P1: per-block LDS histogram over 3x782 buckets -> cntblk[rel][bucket][blk]
__global__ __launch_bounds__(256) void hist_blk_kernel(const int* __restrict__ tt_src,
    const int* __restrict__ tt_dst, const int* __restrict__ ect_d, int* __restrict__ cntblk)
{
  __shared__ int h[3 * NBK];
  const int t = threadIdx.x, b = blockIdx.x;
  for (int i = t; i < 3 * NBK; i += 256) h[i] = 0;
  __syncthreads();
  const int lo = b * CHT, hi = min(lo + CHT, ETT);
  for (int i = lo + t; i < hi; i += 256) {
    atomicAdd(&h[tt_dst[i] >> 7], 1);
    atomicAdd(&h[NBK + (tt_src[i] >> 7)], 1);
  }
  const int lo2 = b * CHC, hi2 = min(lo2 + CHC, ECT);
  for (int i = lo2 + t; i < hi2; i += 256)
    atomicAdd(&h[2 * NBK + (ect_d[i] >> 7)], 1);
  __syncthreads();
  for (int i = t; i < 3 * NBK; i += 256)
    cntblk[(size_t)i * NBLK + b] = h[i];
}

// scan phase B over TOTC elements
__global__ __launch_bounds__(256) void scan2_blk_kernel(const int* __restrict__ in,
    int* __restrict__ out, int* __restrict__ bsum)
{
  const int t = threadIdx.x, b = blockIdx.x;
  const int idx = b * 2048 + t * 8;
  int v[8];
  int s = 0;
  if (idx < TOTC) {
    const int4 q0 = *(const int4*)(in + idx);
    const int4 q1 = *(const int4*)(in + idx + 4);
    int x;
    x = q0.x; v[0] = s; s += x;  x = q0.y; v[1] = s; s += x;
    x = q0.z; v[2] = s; s += x;  x = q0.w; v[3] = s; s += x;
    x = q1.x; v[4] = s; s += x;  x = q1.y; v[5] = s; s += x;
    x = q1.z; v[6] = s; s += x;  x = q1.w; v[7] = s; s += x;
  } else {
    for (int j = 0; j < 8; ++j) v[j] = 0;
  }
  __shared__ int sh[256];
  sh[t] = s;
  __syncthreads();
  for (int d = 1; d < 256; d <<= 1) {
    const int u = (t >= d) ? sh[t - d] : 0;
    __syncthreads();
    sh[t] += u;
    __syncthreads();
  }
  const int excl = (t == 0) ? 0 : sh[t - 1];
  if (idx < TOTC) {
    int4 q0, q1;
    q0.x = excl + v[0]; q0.y = excl + v[1]; q0.z = excl + v[2]; q0.w = excl + v[3];
    q1.x = excl + v[4]; q1.y = excl + v[5]; q1.z = excl + v[6]; q1.w = excl + v[7];
    *(int4*)(out + idx) = q0;
    *(int4*)(out + idx + 4) = q1;
  }
  if (t == 255) bsum[b] = sh[255];
}

// scan phase C: 294 block sums, single block of 512
__global__ __launch_bounds__(512) void scan2_top_kernel(const int* __restrict__ bsum,
    int* __restrict__ bpre)
{
  __shared__ int sh[512];
  const int t = threadIdx.x;
  const int orig = (t < NSB) ? bsum[t] : 0;
  sh[t] = orig;
  __syncthreads();
  for (int d = 1; d < 512; d <<= 1) {
    const int v = (t >= d) ? sh[t - d] : 0;
    __syncthreads();
    sh[t] += v;
    __syncthreads();
  }
  if (t < NSB) bpre[t] = sh[t] - orig;
}

// scan phase D
__global__ __launch_bounds__(256) void scan2_add_kernel(const int* __restrict__ bpre,
    int* __restrict__ out)
{
  const int t = threadIdx.x, b = blockIdx.x;
  const int bp = bpre[b];
  const int idx = b * 2048 + t * 8;
  if (idx < TOTC) {
    int4 q0 = *(const int4*)(out + idx);
    int4 q1 = *(const int4*)(out + idx + 4);
    q0.x += bp; q0.y += bp; q0.z += bp; q0.w += bp;
    q1.x += bp; q1.y += bp; q1.z += bp; q1.w += bp;
    *(int4*)(out + idx) = q0;
    *(int4*)(out + idx + 4) = q1;
  }
}

// P3: append packed (key_local<<17 | payload) into reserved bucket ranges
__global__ __launch_bounds__(256) void bin_kernel(const int* __restrict__ tt_src,
    const int* __restrict__ tt_dst, const int* __restrict__ ect_s, const int* __restrict__ ect_d,
    const int* __restrict__ scanned, u32* __restrict__ bin)
{
  __shared__ int cur[3 * NBK];
  const int t = threadIdx.x, b = blockIdx.x;
  for (int i = t; i < 3 * NBK; i += 256)
    cur[i] = scanned[(size_t)i * NBLK + b];
  __syncthreads();
  const int lo = b * CHT, hi = min(lo + CHT, ETT);
  for (int i = lo + t; i < hi; i += 256) {
    const int s = tt_src[i], d = tt_dst[i];
    int p = atomicAdd(&cur[d >> 7], 1);
    bin[p] = ((u32)(d & 127) << 17) | (u32)s;
    p = atomicAdd(&cur[NBK + (s >> 7)], 1);
    bin[p] = ((u32)(s & 127) << 17) | (u32)d;
  }
  const int lo2 = b * CHC, hi2 = min(lo2 + CHC, ECT);
  for (int i = lo2 + t; i < hi2; i += 256) {
    const int s = ect_s[i], d = ect_d[i];
    const int p = atomicAdd(&cur[2 * NBK + (d >> 7)], 1);
    bin[p] = ((u32)(d & 127) << 17) | (u32)s;
  }
}

// P4: per-bucket counting sort -> node offsets (coalesced) + el (window-local)
__global__ __launch_bounds__(256) void bucket_fill_kernel(const int* __restrict__ scanned,
    const u32* __restrict__ bin, int* __restrict__ offs, int* __restrict__ big_el)
{
  const int rel = blockIdx.x / NBK;
  const int bucket = blockIdx.x - rel * NBK;
  const int t = threadIdx.x;
  __shared__ int s_cnt[128], s_exc[128], s_cur[128];
  if (t < 128) s_cnt[t] = 0;
  __syncthreads();
  const int base = scanned[(size_t)blockIdx.x * NBLK];
  const int nxt = (blockIdx.x == 3 * NBK - 1) ? (2 * ETT + ECT)
                                              : scanned[((size_t)blockIdx.x + 1) * NBLK];
  const int size = nxt - base;
  for (int i = t; i < size; i += 256)
    atomicAdd(&s_cnt[bin[base + i] >> 17], 1);
  __syncthreads();
  if (t < 128) s_exc[t] = s_cnt[t];
  __syncthreads();
  for (int d = 1; d < 128; d <<= 1) {
    int v = 0;
    if (t < 128 && t >= d) v = s_exc[t - d];
    __syncthreads();
    if (t < 128) s_exc[t] += v;
    __syncthreads();
  }
  const int relbase = rel * ETT;                 // 0, ETT, 2*ETT
  const int obase = base - relbase;
  int* off_rel = offs + (size_t)rel * OFFS;
  const int node0 = bucket * 128;
  if (t < 128) {
    const int excl = s_exc[t] - s_cnt[t];        // exclusive within bucket
    s_cur[t] = obase + excl;
    if (node0 + t < NT) off_rel[node0 + t] = obase + excl;
  }
  if (t == 0 && bucket == NBK - 1) off_rel[NT] = obase + size;
  __syncthreads();
  int* el_rel = big_el + relbase;
  for (int i = t; i < size; i += 256) {
    const u32 e = bin[base + i];
    const int pos = atomicAdd(&s_cur[e >> 17], 1);
    el_rel[pos] = (int)(e & 0x1FFFFu);
  }
}

// ---------- K5: fused 3-relation gather, software-pipelined (depth 2) ----------
__device__ __forceinline__ void gat_pipe(const int* __restrict__ off,
    const int* __restrict__ el, const float* __restrict__ aS, const float* __restrict__ aD,
    const u16* __restrict__ hb, int d, int h, int c0, int self_loop, float w,
    float& x0, float& x1)
{
  const float ad = aD[(size_t)d * 4 + h];
  const int beg = off[d];
  const int m = off[d + 1] - beg;     // real edges
  const int cnt = m + self_loop;
  if (cnt <= 0) return;
  float den = 0.f, a0 = 0.f, a1 = 0.f;
  int s_a = (0 < m) ? el[beg] : d;
  int s_b = (1 < m) ? el[beg + 1] : d;
  float e_a = aS[(size_t)s_a * 4 + h];
  u32 p_a = *(const u32*)(hb + (size_t)s_a * 128 + c0);
  for (int k = 0; k < cnt; ++k) {
    const int s_c = (k + 2 < m) ? el[beg + k + 2] : d;
    const float e_b = aS[(size_t)s_b * 4 + h];
    const u32 p_b = *(const u32*)(hb + (size_t)s_b * 128 + c0);
    float ea = e_a + ad;
    ea = ea > 0.f ? ea : SLOPE * ea;
    const float ex = __expf(ea);
    den += ex;
    a0 = fmaf(ex, lof(p_a), a0);
    a1 = fmaf(ex, hif(p_a), a1);
    e_a = e_b; p_a = p_b; s_b = s_c;
  }
  const float inv = den > 0.f ? w / den : 0.f;
  x0 = fmaf(a0, inv, x0);
  x1 = fmaf(a1, inv, x1);
}

__global__ __launch_bounds__(256) void gather_all_kernel(
    const int* __restrict__ off_f, const int* __restrict__ el_f,
    const float* __restrict__ aS_sd, const float* __restrict__ aD_sd, const u16* __restrict__ hs,
    const int* __restrict__ off_r, const int* __restrict__ el_r,
    const float* __restrict__ aS_ds, const float* __restrict__ aD_ds, const u16* __restrict__ hd,
    const int* __restrict__ off_c, const int* __restrict__ el_c,
    const float* __restrict__ aS_ct, const float* __restrict__ aD_ct, const u16* __restrict__ hc,
    const u16* __restrict__ skip, const float* __restrict__ cbias, u16* __restrict__ x)
{
  const int d = blockIdx.x * 4 + (threadIdx.x >> 6);
  if (d >= NT) return;
  const int lane = threadIdx.x & 63;
  const int h = lane >> 4;
  const int c0 = lane * 2;
  float x0 = 0.f, x1 = 0.f;
  gat_pipe(off_f, el_f, aS_sd, aD_sd, hs, d, h, c0, 1, 0.25f, x0, x1);
  gat_pipe(off_r, el_r, aS_ds, aD_ds, hd, d, h, c0, 1, 0.25f, x0, x1);
  gat_pipe(off_c, el_c, aS_ct, aD_ct, hc, d, h, c0, 0, 0.5f, x0, x1);
  const u32 sk = *(const u32*)(skip + (size_t)d * 128 + c0);
  const float2 cb = *(const float2*)(cbias + c0);
  const float o0 = fmaxf(x0 + cb.x + lof(sk), 0.f);
  const float o1 = fmaxf(x1 + cb.y + hif(sk), 0.f);
  *(u32*)(x + (size_t)d * 128 + c0) = (u32)f2bf(o0) | ((u32)f2bf(o1) << 16);
}

extern "C" void kernel_launch(void* const* d_in, const int* in_sizes, int n_in,
                              void* d_out, int out_size, void* d_ws, size_t ws_size,
                              hipStream_t stream)
{
  const float* x_t   = (const float*)d_in[0];
  const float* x_c   = (const float*)d_in[1];
  const int*   e_tt  = (const int*)d_in[2];
  const int*   ect_s = (const int*)d_in[3];
  const int*   ect_d = (const int*)d_in[4];
  const float* Wpt = (const float*)d_in[5];   const float* bpt = (const float*)d_in[6];
  const float* Wpc = (const float*)d_in[7];   const float* bpc = (const float*)d_in[8];
  const float* Wsd = (const float*)d_in[9];   const float* As_sd = (const float*)d_in[10];
  const float* Ad_sd = (const float*)d_in[11]; const float* bsd = (const float*)d_in[12];
  const float* Wds = (const float*)d_in[13];  const float* As_ds = (const float*)d_in[14];
  const float* Ad_ds = (const float*)d_in[15]; const float* bds = (const float*)d_in[16];
  const float* Wcs = (const float*)d_in[17];  const float* Wcd = (const float*)d_in[18];
  const float* As_ct = (const float*)d_in[19]; const float* Ad_ct = (const float*)d_in[20];
  const float* bct = (const float*)d_in[21];
  const float* Wout = (const float*)d_in[22]; const float* bout = (const float*)d_in[23];

  // workspace (~140 MB)
  char* p = (char*)d_ws;
  size_t off = 0;
  auto alloc = [&](size_t bytes) { char* r = p + off; off += (bytes + 255) & ~(size_t)255; return r; };
  u16* ht_bf   = (u16*)alloc((size_t)NT * 128 * 2);
  u16* hs_bf   = (u16*)alloc((size_t)NT * 128 * 2);
  u16* hd_bf   = (u16*)alloc((size_t)NT * 128 * 2);
  u16* hc_bf   = (u16*)alloc((size_t)NC * 128 * 2);
  u16* x_bf    = (u16*)alloc((size_t)NT * 128 * 2);
  float* aS_sd = (float*)alloc((size_t)NT * 4 * 4);
  float* aD_sd = (float*)alloc((size_t)NT * 4 * 4);
  float* aS_ds = (float*)alloc((size_t)NT * 4 * 4);
  float* aD_ds = (float*)alloc((size_t)NT * 4 * 4);
  float* aS_ct = (float*)alloc((size_t)NC * 4 * 4);
  float* aD_ct = (float*)alloc((size_t)NT * 4 * 4);
  int* cntblk  = (int*)alloc((size_t)TOTC * 4);
  int* scanned = (int*)alloc((size_t)TOTC * 4);
  u32* bin     = (u32*)alloc((size_t)(2 * ETT + ECT) * 4);
  int* big_el  = (int*)alloc((size_t)(2 * ETT + ECT) * 4);
  int* offs    = (int*)alloc((size_t)3 * OFFS * 4);
  int* bsum    = (int*)alloc((size_t)NSB * 4);
  int* bpre    = (int*)alloc((size_t)NSB * 4);
  float* fold_cd = (float*)alloc(512 * 4);
  float* cbias   = (float*)alloc(128 * 4);
  u16* bfrag_sd  = (u16*)alloc((size_t)9 * 4 * 64 * 8 * 2);
  u16* bfrag_ds  = (u16*)alloc((size_t)9 * 4 * 64 * 8 * 2);
  u16* bfrag_out = (u16*)alloc((size_t)8 * 4 * 64 * 8 * 2);

  int* off_f = offs;
  int* off_r = offs + OFFS;
  int* off_c = offs + 2 * OFFS;
  int* el_f = big_el;
  int* el_r = big_el + ETT;
  int* el_c = big_el + 2 * ETT;

  const int* tt_src = e_tt;
  const int* tt_dst = e_tt + ETT;

  const int gT = (NT + 31) / 32;       // 3125
  const int gC = (NC + 31) / 32;       // 782
  const int gM = (NT + 63) / 64;       // 1563 (MFMA blocks)

  // CSR build (bucket-binned counting sort, no global atomics)
  hist_blk_kernel<<<NBLK, 256, 0, stream>>>(tt_src, tt_dst, ect_d, cntblk);
  scan2_blk_kernel<<<NSB, 256, 0, stream>>>(cntblk, scanned, bsum);
  scan2_top_kernel<<<1, 512, 0, stream>>>(bsum, bpre);
  scan2_add_kernel<<<NSB, 256, 0, stream>>>(bpre, scanned);
  bin_kernel<<<NBLK, 256, 0, stream>>>(tt_src, tt_dst, ect_s, ect_d, scanned, bin);
  bucket_fill_kernel<<<3 * NBK, 256, 0, stream>>>(scanned, bin, offs, big_el);

  // weight prep: MFMA frag layouts + fold_cd + cbias
  prep_bfrag_kernel<<<3, 256, 0, stream>>>(Wsd, As_sd, Ad_sd, Wds, As_ds, Ad_ds, Wout,
                                           bfrag_sd, bfrag_ds, bfrag_out);
  fold_all_kernel<<<2, 128, 0, stream>>>(Wcd, Ad_ct, bsd, bds, bct, fold_cd, cbias);

  // node transforms
  pre_t_kernel<<<gT, 256, 0, stream>>>(x_t, Wpt, bpt, fold_cd, ht_bf, aD_ct, NT);
  mfma_logits_kernel<<<gM, 256, 0, stream>>>((const short*)ht_bf, (const short*)bfrag_sd,
                                             hs_bf, aS_sd, aD_sd, NT);
  mfma_logits_kernel<<<gM, 256, 0, stream>>>((const short*)ht_bf, (const short*)bfrag_ds,
                                             hd_bf, aS_ds, aD_ds, NT);
  ctx_kernel<<<gC, 256, 0, stream>>>(x_c, Wpc, bpc, Wcs, As_ct, hc_bf, aS_ct, NC);

  // fused gather (sd + ds + ct + cbias + skip + relu) -> x_bf
  gather_all_kernel<<<(NT + 3) / 4, 256, 0, stream>>>(
      off_f, el_f, aS_sd, aD_sd, hs_bf,
      off_r, el_r, aS_ds, aD_ds, hd_bf,
      off_c, el_c, aS_ct, aD_ct, hc_bf,
      ht_bf, cbias, x_bf);

  // final MFMA GEMM -> d_out (fp32)
  mfma_out_kernel<<<gM, 256, 0, stream>>>((const short*)x_bf, (const short*)bfrag_out,
                                          bout, (float*)d_out, NT);
}

// Round 7
// 431.816 us; speedup vs baseline: 10.0966x; 1.1845x over previous
//
#include <hip/hip_runtime.h>
#include <cstdint>
#include <cstddef>

typedef unsigned short u16;
typedef unsigned int u32;

#define NT 100000
#define NC 25000
#define ETT 800000
#define ECT 400000
#define SLOPE 0.2f
#define OFFS (NT + 4)           // padded stride for offset arrays (16B-aligned)

// bucket-binned CSR build
#define NBK 782                 // ceil(NT/128) buckets of 128 nodes
#define NBLK 256                // binning blocks
#define CHT ((ETT + NBLK - 1) / NBLK)   // 3125 tt edges / block
#define CHC ((ECT + NBLK - 1) / NBLK)   // 1563 ct edges / block
#define TOTC (3 * NBK * NBLK)           // 600576 counts
#define NSB ((TOTC + 2047) / 2048)      // 294 scan blocks

typedef __attribute__((ext_vector_type(8))) short bf16x8;
typedef __attribute__((ext_vector_type(4))) float f32x4;

__device__ __forceinline__ u16 f2bf(float f) {
  u32 u = __float_as_uint(f);
  u32 r = (u >> 16) & 1u;
  return (u16)((u + 0x7fffu + r) >> 16);
}
__device__ __forceinline__ float lof(u32 p) { return __uint_as_float(p << 16); }
__device__ __forceinline__ float hif(u32 p) { return __uint_as_float(p & 0xffff0000u); }

// ---------- K1: h_t(bf16) = relu(x_t @ Wpt + b); aD_ct = relu(h_t) @ fold_cd ----------
__global__ __launch_bounds__(256) void pre_t_kernel(const float* __restrict__ in,
    const float* __restrict__ W, const float* __restrict__ bias,
    const float* __restrict__ fold_cd, u16* __restrict__ h_t,
    float* __restrict__ aD, int N)
{
  __shared__ float s_in[32][33];
  __shared__ float s_W[32][128];
  __shared__ float s_fold[512];
  const int t = threadIdx.x;
  s_fold[t] = fold_cd[t];
  s_fold[t + 256] = fold_cd[t + 256];
  const int row0 = blockIdx.x * 32;
  const int rl = t >> 3, cg = t & 7;
  const int gr = row0 + rl;
  float acc[4][4];
  for (int g = 0; g < 4; ++g)
    for (int j = 0; j < 4; ++j)
      acc[g][j] = bias[g * 32 + cg * 4 + j];
  for (int kc = 0; kc < 64; kc += 32) {
    {
      float4 f = make_float4(0.f, 0.f, 0.f, 0.f);
      if (gr < N) f = *(const float4*)(in + (size_t)gr * 64 + kc + cg * 4);
      s_in[rl][cg * 4 + 0] = f.x; s_in[rl][cg * 4 + 1] = f.y;
      s_in[rl][cg * 4 + 2] = f.z; s_in[rl][cg * 4 + 3] = f.w;
    }
    for (int j = 0; j < 4; ++j) {
      const int idx = t + j * 256;
      const int k = idx >> 5, c4 = (idx & 31) * 4;
      *(float4*)&s_W[k][c4] = *(const float4*)(W + (size_t)(kc + k) * 128 + c4);
    }
    __syncthreads();
#pragma unroll 8
    for (int k = 0; k < 32; ++k) {
      const float a = s_in[rl][k];
      for (int g = 0; g < 4; ++g) {
        const float4 w = *(const float4*)&s_W[k][g * 32 + cg * 4];
        acc[g][0] = fmaf(a, w.x, acc[g][0]);
        acc[g][1] = fmaf(a, w.y, acc[g][1]);
        acc[g][2] = fmaf(a, w.z, acc[g][2]);
        acc[g][3] = fmaf(a, w.w, acc[g][3]);
      }
    }
    __syncthreads();
  }
  if (gr < N) {
    float p0 = 0.f, p1 = 0.f, p2 = 0.f, p3 = 0.f;
    for (int g = 0; g < 4; ++g) {
      for (int j = 0; j < 4; ++j) acc[g][j] = fmaxf(acc[g][j], 0.f);
      uint2 pk;
      pk.x = (u32)f2bf(acc[g][0]) | ((u32)f2bf(acc[g][1]) << 16);
      pk.y = (u32)f2bf(acc[g][2]) | ((u32)f2bf(acc[g][3]) << 16);
      *(uint2*)(h_t + (size_t)gr * 128 + g * 32 + cg * 4) = pk;
      for (int j = 0; j < 4; ++j) {
        const int col = g * 32 + cg * 4 + j;
        const float4 f4 = *(const float4*)&s_fold[col * 4];
        const float a = acc[g][j];
        p0 = fmaf(a, f4.x, p0); p1 = fmaf(a, f4.y, p1);
        p2 = fmaf(a, f4.z, p2); p3 = fmaf(a, f4.w, p3);
      }
    }
    for (int m = 1; m < 8; m <<= 1) {
      p0 += __shfl_xor(p0, m); p1 += __shfl_xor(p1, m);
      p2 += __shfl_xor(p2, m); p3 += __shfl_xor(p3, m);
    }
    if (cg == 0) *(float4*)(aD + (size_t)gr * 4) = make_float4(p0, p1, p2, p3);
  }
}

// ---------- weight prep: frag-linear bf16 B for MFMA (+ fold cols) + fold_cd + cbias ----------
__global__ __launch_bounds__(256) void prep_kernel(
    const float* __restrict__ Wsd, const float* __restrict__ AsSd, const float* __restrict__ AdSd,
    const float* __restrict__ Wds, const float* __restrict__ AsDs, const float* __restrict__ AdDs,
    const float* __restrict__ Wout, u16* __restrict__ bf_sd, u16* __restrict__ bf_ds,
    u16* __restrict__ bf_out,
    const float* __restrict__ Wcd, const float* __restrict__ attD,
    const float* __restrict__ bsd, const float* __restrict__ bds, const float* __restrict__ bct,
    float* __restrict__ fold_cd, float* __restrict__ cbias)
{
  const int b = blockIdx.x;
  const int tid = threadIdx.x;
  if (b == 3) {
    if (tid < 128) {
      for (int h = 0; h < 4; ++h) {
        float s = 0.f;
        for (int c = 0; c < 32; ++c)
          s = fmaf(Wcd[tid * 128 + h * 32 + c], attD[h * 32 + c], s);
        fold_cd[tid * 4 + h] = s;
      }
      cbias[tid] = 0.25f * bsd[tid] + 0.25f * bds[tid] + 0.5f * bct[tid];
    }
    return;
  }
  __shared__ float fS[512], fD[512];
  const float* W = (b == 0) ? Wsd : (b == 1) ? Wds : Wout;
  const float* As = (b == 0) ? AsSd : AsDs;
  const float* Ad = (b == 0) ? AdSd : AdDs;
  u16* out = (b == 0) ? bf_sd : (b == 1) ? bf_ds : bf_out;
  const int tiles = (b == 2) ? 8 : 9;
  if (b < 2) {
    if (tid < 128) {
      for (int h = 0; h < 4; ++h) {
        float s1 = 0.f, s2 = 0.f;
        for (int c = 0; c < 32; ++c) {
          const float wv = W[tid * 128 + h * 32 + c];
          s1 = fmaf(wv, As[h * 32 + c], s1);
          s2 = fmaf(wv, Ad[h * 32 + c], s2);
        }
        fS[tid * 4 + h] = s1; fD[tid * 4 + h] = s2;
      }
    }
    __syncthreads();
  }
  const int total = tiles * 4 * 64 * 8;
  for (int i = tid; i < total; i += 256) {
    const int j = i & 7, lane = (i >> 3) & 63, ks = (i >> 9) & 3, t = i >> 11;
    const int k = ks * 32 + (lane >> 4) * 8 + j;
    const int n = t * 16 + (lane & 15);
    float v;
    if (n < 128) v = W[k * 128 + n];
    else if (n < 132) v = fS[k * 4 + (n - 128)];
    else if (n < 136) v = fD[k * 4 + (n - 132)];
    else v = 0.f;
    out[i] = f2bf(v);
  }
}

// ---------- fused MFMA GEMM x2 (sd + ds), N=144 each: bf16 out + aS/aD logits ----------
__global__ __launch_bounds__(256) void mfma_logits2_kernel(
    const short* __restrict__ A, const short* __restrict__ Bsd, const short* __restrict__ Bds,
    u16* __restrict__ hs, float* __restrict__ aSsd, float* __restrict__ aDsd,
    u16* __restrict__ hd, float* __restrict__ aSds, float* __restrict__ aDds, int M)
{
  __shared__ __align__(16) float lds[4][16][148];
  const int wv = threadIdx.x >> 6, lane = threadIdx.x & 63;
  const int quad = lane >> 4, l16 = lane & 15;
  const int row0 = blockIdx.x * 64 + wv * 16;
  const int arow = min(row0 + l16, M - 1);
  const short* ap = A + (size_t)arow * 128 + quad * 8;
  bf16x8 af[4];
  for (int ks = 0; ks < 4; ++ks) af[ks] = *(const bf16x8*)(ap + ks * 32);
  const int row = row0 + l16;
  const int idx = lane & 7, rr = lane >> 3;
  for (int pass = 0; pass < 2; ++pass) {
    const short* B = pass ? Bds : Bsd;
    u16* outb = pass ? hd : hs;
    float* aS = pass ? aSds : aSsd;
    float* aD = pass ? aDds : aDsd;
    f32x4 acc[9];
    for (int t = 0; t < 9; ++t) acc[t] = (f32x4){0.f, 0.f, 0.f, 0.f};
    for (int ks = 0; ks < 4; ++ks)
      for (int t = 0; t < 9; ++t) {
        const bf16x8 bf = *(const bf16x8*)(B + ((t * 4 + ks) * 64 + lane) * 8);
        acc[t] = __builtin_amdgcn_mfma_f32_16x16x32_bf16(af[ks], bf, acc[t], 0, 0, 0);
      }
    for (int t = 0; t < 9; ++t)
      for (int r = 0; r < 4; ++r)
        lds[wv][quad * 4 + r][t * 16 + l16] = acc[t][r];
    __syncthreads();
    if (row < M) {
      for (int g = 0; g < 8; ++g) {
        const f32x4 v = *(const f32x4*)&lds[wv][l16][g * 16 + quad * 4];
        uint2 pk;
        pk.x = (u32)f2bf(v[0]) | ((u32)f2bf(v[1]) << 16);
        pk.y = (u32)f2bf(v[2]) | ((u32)f2bf(v[3]) << 16);
        *(uint2*)(outb + (size_t)row * 128 + g * 16 + quad * 4) = pk;
      }
    }
    for (int p = 0; p < 2; ++p) {
      const int lr = p * 8 + rr;
      const int n = row0 + lr;
      if (n < M) {
        const float v = lds[wv][lr][128 + idx];
        if (idx < 4) aS[(size_t)n * 4 + idx] = v;
        else aD[(size_t)n * 4 + idx - 4] = v;
      }
    }
    __syncthreads();
  }
}

// ---------- MFMA GEMM, N=128 (8 tiles) + bias -> fp32 out ----------
__global__ __launch_bounds__(256) void mfma_out_kernel(
    const short* __restrict__ A, const short* __restrict__ B,
    const float* __restrict__ bias, float* __restrict__ out, int M)
{
  __shared__ __align__(16) float lds[4][16][132];
  const int wv = threadIdx.x >> 6, lane = threadIdx.x & 63;
  const int quad = lane >> 4, l16 = lane & 15;
  const int row0 = blockIdx.x * 64 + wv * 16;
  const int arow = min(row0 + l16, M - 1);
  const short* ap = A + (size_t)arow * 128 + quad * 8;
  bf16x8 af[4];
  for (int ks = 0; ks < 4; ++ks) af[ks] = *(const bf16x8*)(ap + ks * 32);
  f32x4 acc[8];
  for (int t = 0; t < 8; ++t) acc[t] = (f32x4){0.f, 0.f, 0.f, 0.f};
  for (int ks = 0; ks < 4; ++ks)
    for (int t = 0; t < 8; ++t) {
      const bf16x8 bf = *(const bf16x8*)(B + ((t * 4 + ks) * 64 + lane) * 8);
      acc[t] = __builtin_amdgcn_mfma_f32_16x16x32_bf16(af[ks], bf, acc[t], 0, 0, 0);
    }
  for (int t = 0; t < 8; ++t)
    for (int r = 0; r < 4; ++r)
      lds[wv][quad * 4 + r][t * 16 + l16] = acc[t][r];
  __syncthreads();
  const int row = row0 + l16;
  if (row < M) {
    for (int g = 0; g < 8; ++g) {
      const int col = g * 16 + quad * 4;
      f32x4 v = *(const f32x4*)&lds[wv][l16][col];
      const f32x4 b4 = *(const f32x4*)(bias + col);
      v = v + b4;
      *(f32x4*)(out + (size_t)row * 128 + col) = v;
    }
  }
}

// ---------- K4: hcs = relu(x_c @ Wpc + b) @ Wcs (bf16) + a_s_ct ----------
__global__ __launch_bounds__(256) void ctx_kernel(const float* __restrict__ x_c,
    const float* __restrict__ Wpc, const float* __restrict__ bpc,
    const float* __restrict__ Wcs, const float* __restrict__ attS,
    u16* __restrict__ hc_bf, float* __restrict__ aS, int N)
{
  __shared__ float s_in[32][33];
  __shared__ float s_W[32][128];
  __shared__ float s_h[32][132];
  const int t = threadIdx.x;
  const int row0 = blockIdx.x * 32;
  const int rl = t >> 3, cg = t & 7;
  const int gr = row0 + rl;
  {
    float4 f = make_float4(0.f, 0.f, 0.f, 0.f);
    if (gr < N) f = *(const float4*)(x_c + (size_t)gr * 32 + cg * 4);
    s_in[rl][cg * 4 + 0] = f.x; s_in[rl][cg * 4 + 1] = f.y;
    s_in[rl][cg * 4 + 2] = f.z; s_in[rl][cg * 4 + 3] = f.w;
  }
  for (int j = 0; j < 4; ++j) {
    const int idx = t + j * 256;
    const int k = idx >> 5, c4 = (idx & 31) * 4;
    *(float4*)&s_W[k][c4] = *(const float4*)(Wpc + (size_t)k * 128 + c4);
  }
  __syncthreads();
  float acc[4][4];
  for (int g = 0; g < 4; ++g)
    for (int j = 0; j < 4; ++j) acc[g][j] = bpc[g * 32 + cg * 4 + j];
#pragma unroll 8
  for (int k = 0; k < 32; ++k) {
    const float a = s_in[rl][k];
    for (int g = 0; g < 4; ++g) {
      const float4 w = *(const float4*)&s_W[k][g * 32 + cg * 4];
      acc[g][0] = fmaf(a, w.x, acc[g][0]);
      acc[g][1] = fmaf(a, w.y, acc[g][1]);
      acc[g][2] = fmaf(a, w.z, acc[g][2]);
      acc[g][3] = fmaf(a, w.w, acc[g][3]);
    }
  }
  for (int g = 0; g < 4; ++g)
    *(float4*)&s_h[rl][g * 32 + cg * 4] =
        make_float4(fmaxf(acc[g][0], 0.f), fmaxf(acc[g][1], 0.f),
                    fmaxf(acc[g][2], 0.f), fmaxf(acc[g][3], 0.f));
  __syncthreads();
  float acc2[4][4];
  for (int g = 0; g < 4; ++g)
    for (int j = 0; j < 4; ++j) acc2[g][j] = 0.f;
  for (int kc = 0; kc < 128; kc += 32) {
    for (int j = 0; j < 4; ++j) {
      const int idx = t + j * 256;
      const int k = idx >> 5, c4 = (idx & 31) * 4;
      *(float4*)&s_W[k][c4] = *(const float4*)(Wcs + (size_t)(kc + k) * 128 + c4);
    }
    __syncthreads();
#pragma unroll 8
    for (int k = 0; k < 32; ++k) {
      const float a = s_h[rl][kc + k];
      for (int g = 0; g < 4; ++g) {
        const float4 w = *(const float4*)&s_W[k][g * 32 + cg * 4];
        acc2[g][0] = fmaf(a, w.x, acc2[g][0]);
        acc2[g][1] = fmaf(a, w.y, acc2[g][1]);
        acc2[g][2] = fmaf(a, w.z, acc2[g][2]);
        acc2[g][3] = fmaf(a, w.w, acc2[g][3]);
      }
    }
    __syncthreads();
  }
  if (gr < N) {
    float pS[4];
    for (int g = 0; g < 4; ++g) {
      uint2 pk;
      pk.x = (u32)f2bf(acc2[g][0]) | ((u32)f2bf(acc2[g][1]) << 16);
      pk.y = (u32)f2bf(acc2[g][2]) | ((u32)f2bf(acc2[g][3]) << 16);
      *(uint2*)(hc_bf + (size_t)gr * 128 + g * 32 + cg * 4) = pk;
      const float4 as4 = *(const float4*)(attS + g * 32 + cg * 4);
      pS[g] = acc2[g][0] * as4.x + acc2[g][1] * as4.y + acc2[g][2] * as4.z + acc2[g][3] * as4.w;
    }
    for (int m = 1; m < 8; m <<= 1)
      for (int g = 0; g < 4; ++g) pS[g] += __shfl_xor(pS[g], m);
    if (cg == 0)
      *(float4*)(aS + (size_t)gr * 4) = make_float4(pS[0], pS[1], pS[2], pS[3]);
  }
}

// ---------- bucket-binned CSR build (no global atomics) ----------
__global__ __launch_bounds__(256) void hist_blk_kernel(const int* __restrict__ tt_src,
    const int* __restrict__ tt_dst, const int* __restrict__ ect_d, int* __restrict__ cntblk)
{
  __shared__ int h[3 * NBK];
  const int t = threadIdx.x, b = blockIdx.x;
  for (int i = t; i < 3 * NBK; i += 256) h[i] = 0;
  __syncthreads();
  const int lo = b * CHT, hi = min(lo + CHT, ETT);
  for (int i = lo + t; i < hi; i += 256) {
    atomicAdd(&h[tt_dst[i] >> 7], 1);
    atomicAdd(&h[NBK + (tt_src[i] >> 7)], 1);
  }
  const int lo2 = b * CHC, hi2 = min(lo2 + CHC, ECT);
  for (int i = lo2 + t; i < hi2; i += 256)
    atomicAdd(&h[2 * NBK + (ect_d[i] >> 7)], 1);
  __syncthreads();
  for (int i = t; i < 3 * NBK; i += 256)
    cntblk[(size_t)i * NBLK + b] = h[i];
}

__global__ __launch_bounds__(256) void scan2_blk_kernel(const int* __restrict__ in,
    int* __restrict__ out, int* __restrict__ bsum)
{
  const int t = threadIdx.x, b = blockIdx.x;
  const int idx = b * 2048 + t * 8;
  int v[8];
  int s = 0;
  if (idx < TOTC) {
    const int4 q0 = *(const int4*)(in + idx);
    const int4 q1 = *(const int4*)(in + idx + 4);
    int x;
    x = q0.x; v[0] = s; s += x;  x = q0.y; v[1] = s; s += x;
    x = q0.z; v[2] = s; s += x;  x = q0.w; v[3] = s; s += x;
    x = q1.x; v[4] = s; s += x;  x = q1.y; v[5] = s; s += x;
    x = q1.z; v[6] = s; s += x;  x = q1.w; v[7] = s; s += x;
  } else {
    for (int j = 0; j < 8; ++j) v[j] = 0;
  }
  __shared__ int sh[256];
  sh[t] = s;
  __syncthreads();
  for (int d = 1; d < 256; d <<= 1) {
    const int u = (t >= d) ? sh[t - d] : 0;
    __syncthreads();
    sh[t] += u;
    __syncthreads();
  }
  const int excl = (t == 0) ? 0 : sh[t - 1];
  if (idx < TOTC) {
    int4 q0, q1;
    q0.x = excl + v[0]; q0.y = excl + v[1]; q0.z = excl + v[2]; q0.w = excl + v[3];
    q1.x = excl + v[4]; q1.y = excl + v[5]; q1.z = excl + v[6]; q1.w = excl + v[7];
    *(int4*)(out + idx) = q0;
    *(int4*)(out + idx + 4) = q1;
  }
  if (t == 255) bsum[b] = sh[255];
}

__global__ __launch_bounds__(512) void scan2_top_kernel(const int* __restrict__ bsum,
    int* __restrict__ bpre)
{
  __shared__ int sh[512];
  const int t = threadIdx.x;
  const int orig = (t < NSB) ? bsum[t] : 0;
  sh[t] = orig;
  __syncthreads();
  for (int d = 1; d < 512; d <<= 1) {
    const int v = (t >= d) ? sh[t - d] : 0;
    __syncthreads();
    sh[t] += v;
    __syncthreads();
  }
  if (t < NSB) bpre[t] = sh[t] - orig;
}

__global__ __launch_bounds__(256) void scan2_add_kernel(const int* __restrict__ bpre,
    int* __restrict__ out)
{
  const int t = threadIdx.x, b = blockIdx.x;
  const int bp = bpre[b];
  const int idx = b * 2048 + t * 8;
  if (idx < TOTC) {
    int4 q0 = *(const int4*)(out + idx);
    int4 q1 = *(const int4*)(out + idx + 4);
    q0.x += bp; q0.y += bp; q0.z += bp; q0.w += bp;
    q1.x += bp; q1.y += bp; q1.z += bp; q1.w += bp;
    *(int4*)(out + idx) = q0;
    *(int4*)(out + idx + 4) = q1;
  }
}

__global__ __launch_bounds__(256) void bin_kernel(const int* __restrict__ tt_src,
    const int* __restrict__ tt_dst, const int* __restrict__ ect_s, const int* __restrict__ ect_d,
    const int* __restrict__ scanned, u32* __restrict__ bin)
{
  __shared__ int cur[3 * NBK];
  const int t = threadIdx.x, b = blockIdx.x;
  for (int i = t; i < 3 * NBK; i += 256)
    cur[i] = scanned[(size_t)i * NBLK + b];
  __syncthreads();
  const int lo = b * CHT, hi = min(lo + CHT, ETT);
  for (int i = lo + t; i < hi; i += 256) {
    const int s = tt_src[i], d = tt_dst[i];
    int p = atomicAdd(&cur[d >> 7], 1);
    bin[p] = ((u32)(d & 127) << 17) | (u32)s;
    p = atomicAdd(&cur[NBK + (s >> 7)], 1);
    bin[p] = ((u32)(s & 127) << 17) | (u32)d;
  }
  const int lo2 = b * CHC, hi2 = min(lo2 + CHC, ECT);
  for (int i = lo2 + t; i < hi2; i += 256) {
    const int s = ect_s[i], d = ect_d[i];
    const int p = atomicAdd(&cur[2 * NBK + (d >> 7)], 1);
    bin[p] = ((u32)(d & 127) << 17) | (u32)s;
  }
}

__global__ __launch_bounds__(256) void bucket_fill_kernel(const int* __restrict__ scanned,
    const u32* __restrict__ bin, int* __restrict__ offs, int* __restrict__ big_el)
{
  const int rel = blockIdx.x / NBK;
  const int bucket = blockIdx.x - rel * NBK;
  const int t = threadIdx.x;
  __shared__ int s_cnt[128], s_exc[128], s_cur[128];
  if (t < 128) s_cnt[t] = 0;
  __syncthreads();
  const int base = scanned[(size_t)blockIdx.x * NBLK];
  const int nxt = (blockIdx.x == 3 * NBK - 1) ? (2 * ETT + ECT)
                                              : scanned[((size_t)blockIdx.x + 1) * NBLK];
  const int size = nxt - base;
  for (int i = t; i < size; i += 256)
    atomicAdd(&s_cnt[bin[base + i] >> 17], 1);
  __syncthreads();
  if (t < 128) s_exc[t] = s_cnt[t];
  __syncthreads();
  for (int d = 1; d < 128; d <<= 1) {
    int v = 0;
    if (t < 128 && t >= d) v = s_exc[t - d];
    __syncthreads();
    if (t < 128) s_exc[t] += v;
    __syncthreads();
  }
  const int relbase = rel * ETT;
  const int obase = base - relbase;
  int* off_rel = offs + (size_t)rel * OFFS;
  const int node0 = bucket * 128;
  if (t < 128) {
    const int excl = s_exc[t] - s_cnt[t];
    s_cur[t] = obase + excl;
    if (node0 + t < NT) off_rel[node0 + t] = obase + excl;
  }
  if (t == 0 && bucket == NBK - 1) off_rel[NT] = obase + size;
  __syncthreads();
  int* el_rel = big_el + relbase;
  for (int i = t; i < size; i += 256) {
    const u32 e = bin[base + i];
    const int pos = atomicAdd(&s_cur[e >> 17], 1);
    el_rel[pos] = (int)(e & 0x1FFFFu);
  }
}

// ---------- K5: fused 3-relation gather; 16-lane group per dst, 8 ch/lane ----------
__device__ __forceinline__ void gat_pipe16(const int* __restrict__ off,
    const int* __restrict__ el, const float* __restrict__ aS, const float* __restrict__ aD,
    const u16* __restrict__ hb, int d, int h, int cb, int self_loop, float w,
    float* __restrict__ acc)
{
  const float ad = aD[(size_t)d * 4 + h];
  const int beg = off[d];
  const int m = off[d + 1] - beg;     // real edges
  const int cnt = m + self_loop;
  if (cnt <= 0) return;
  float den = 0.f;
  float a0 = 0.f, a1 = 0.f, a2 = 0.f, a3 = 0.f, a4 = 0.f, a5 = 0.f, a6 = 0.f, a7 = 0.f;
  int sB = (1 < m) ? el[beg + 1] : d;
  {
    const int sA0 = (0 < m) ? el[beg] : d;
    float eA = aS[(size_t)sA0 * 4 + h];
    uint4 pA = *(const uint4*)(hb + (size_t)sA0 * 128 + cb);
    for (int k = 0; k < cnt; ++k) {
      const int sC = (k + 2 < m) ? el[beg + k + 2] : d;
      const float eB = aS[(size_t)sB * 4 + h];
      const uint4 pB = *(const uint4*)(hb + (size_t)sB * 128 + cb);
      float ea = eA + ad;
      ea = ea > 0.f ? ea : SLOPE * ea;
      const float ex = __expf(ea);
      den += ex;
      a0 = fmaf(ex, lof(pA.x), a0); a1 = fmaf(ex, hif(pA.x), a1);
      a2 = fmaf(ex, lof(pA.y), a2); a3 = fmaf(ex, hif(pA.y), a3);
      a4 = fmaf(ex, lof(pA.z), a4); a5 = fmaf(ex, hif(pA.z), a5);
      a6 = fmaf(ex, lof(pA.w), a6); a7 = fmaf(ex, hif(pA.w), a7);
      eA = eB; pA = pB; sB = sC;
    }
  }
  const float s = w / den;            // den > 0 since cnt > 0
  acc[0] = fmaf(a0, s, acc[0]); acc[1] = fmaf(a1, s, acc[1]);
  acc[2] = fmaf(a2, s, acc[2]); acc[3] = fmaf(a3, s, acc[3]);
  acc[4] = fmaf(a4, s, acc[4]); acc[5] = fmaf(a5, s, acc[5]);
  acc[6] = fmaf(a6, s, acc[6]); acc[7] = fmaf(a7, s, acc[7]);
}

__global__ __launch_bounds__(256) void gather_all_kernel(
    const int* __restrict__ off_f, const int* __restrict__ el_f,
    const float* __restrict__ aS_sd, const float* __restrict__ aD_sd, const u16* __restrict__ hs,
    const int* __restrict__ off_r, const int* __restrict__ el_r,
    const float* __restrict__ aS_ds, const float* __restrict__ aD_ds, const u16* __restrict__ hd,
    const int* __restrict__ off_c, const int* __restrict__ el_c,
    const float* __restrict__ aS_ct, const float* __restrict__ aD_ct, const u16* __restrict__ hc,
    const u16* __restrict__ skip, const float* __restrict__ cbias, u16* __restrict__ x)
{
  const int d = blockIdx.x * 16 + (threadIdx.x >> 4);
  if (d >= NT) return;
  const int lg = threadIdx.x & 15;    // lane in group
  const int h = lg >> 2;              // head for this lane's channels
  const int cb = lg * 8;              // channel base (8 channels per lane)
  float acc[8];
  for (int i = 0; i < 8; ++i) acc[i] = 0.f;
  gat_pipe16(off_f, el_f, aS_sd, aD_sd, hs, d, h, cb, 1, 0.25f, acc);
  gat_pipe16(off_r, el_r, aS_ds, aD_ds, hd, d, h, cb, 1, 0.25f, acc);
  gat_pipe16(off_c, el_c, aS_ct, aD_ct, hc, d, h, cb, 0, 0.5f, acc);
  const uint4 sk = *(const uint4*)(skip + (size_t)d * 128 + cb);
  const float4 cb0 = *(const float4*)(cbias + cb);
  const float4 cb1 = *(const float4*)(cbias + cb + 4);
  const float o0 = fmaxf(acc[0] + cb0.x + lof(sk.x), 0.f);
  const float o1 = fmaxf(acc[1] + cb0.y + hif(sk.x), 0.f);
  const float o2 = fmaxf(acc[2] + cb0.z + lof(sk.y), 0.f);
  const float o3 = fmaxf(acc[3] + cb0.w + hif(sk.y), 0.f);
  const float o4 = fmaxf(acc[4] + cb1.x + lof(sk.z), 0.f);
  const float o5 = fmaxf(acc[5] + cb1.y + hif(sk.z), 0.f);
  const float o6 = fmaxf(acc[6] + cb1.z + lof(sk.w), 0.f);
  const float o7 = fmaxf(acc[7] + cb1.w + hif(sk.w), 0.f);
  uint4 r;
  r.x = (u32)f2bf(o0) | ((u32)f2bf(o1) << 16);
  r.y = (u32)f2bf(o2) | ((u32)f2bf(o3) << 16);
  r.z = (u32)f2bf(o4) | ((u32)f2bf(o5) << 16);
  r.w = (u32)f2bf(o6) | ((u32)f2bf(o7) << 16);
  *(uint4*)(x + (size_t)d * 128 + cb) = r;
}

extern "C" void kernel_launch(void* const* d_in, const int* in_sizes, int n_in,
                              void* d_out, int out_size, void* d_ws, size_t ws_size,
                              hipStream_t stream)
{
  const float* x_t   = (const float*)d_in[0];
  const float* x_c   = (const float*)d_in[1];
  const int*   e_tt  = (const int*)d_in[2];
  const int*   ect_s = (const int*)d_in[3];
  const int*   ect_d = (const int*)d_in[4];
  const float* Wpt = (const float*)d_in[5];   const float* bpt = (const float*)d_in[6];
  const float* Wpc = (const float*)d_in[7];   const float* bpc = (const float*)d_in[8];
  const float* Wsd = (const float*)d_in[9];   const float* As_sd = (const float*)d_in[10];
  const float* Ad_sd = (const float*)d_in[11]; const float* bsd = (const float*)d_in[12];
  const float* Wds = (const float*)d_in[13];  const float* As_ds = (const float*)d_in[14];
  const float* Ad_ds = (const float*)d_in[15]; const float* bds = (const float*)d_in[16];
  const float* Wcs = (const float*)d_in[17];  const float* Wcd = (const float*)d_in[18];
  const float* As_ct = (const float*)d_in[19]; const float* Ad_ct = (const float*)d_in[20];
  const float* bct = (const float*)d_in[21];
  const float* Wout = (const float*)d_in[22]; const float* bout = (const float*)d_in[23];

  // workspace (~140 MB)
  char* p = (char*)d_ws;
  size_t off = 0;
  auto alloc = [&](size_t bytes) { char* r = p + off; off += (bytes + 255) & ~(size_t)255; return r; };
  u16* ht_bf   = (u16*)alloc((size_t)NT * 128 * 2);
  u16* hs_bf   = (u16*)alloc((size_t)NT * 128 * 2);
  u16* hd_bf   = (u16*)alloc((size_t)NT * 128 * 2);
  u16* hc_bf   = (u16*)alloc((size_t)NC * 128 * 2);
  u16* x_bf    = (u16*)alloc((size_t)NT * 128 * 2);
  float* aS_sd = (float*)alloc((size_t)NT * 4 * 4);
  float* aD_sd = (float*)alloc((size_t)NT * 4 * 4);
  float* aS_ds = (float*)alloc((size_t)NT * 4 * 4);
  float* aD_ds = (float*)alloc((size_t)NT * 4 * 4);
  float* aS_ct = (float*)alloc((size_t)NC * 4 * 4);
  float* aD_ct = (float*)alloc((size_t)NT * 4 * 4);
  int* cntblk  = (int*)alloc((size_t)TOTC * 4);
  int* scanned = (int*)alloc((size_t)TOTC * 4);
  u32* bin     = (u32*)alloc((size_t)(2 * ETT + ECT) * 4);
  int* big_el  = (int*)alloc((size_t)(2 * ETT + ECT) * 4);
  int* offs    = (int*)alloc((size_t)3 * OFFS * 4);
  int* bsum    = (int*)alloc((size_t)NSB * 4);
  int* bpre    = (int*)alloc((size_t)NSB * 4);
  float* fold_cd = (float*)alloc(512 * 4);
  float* cbias   = (float*)alloc(128 * 4);
  u16* bfrag_sd  = (u16*)alloc((size_t)9 * 4 * 64 * 8 * 2);
  u16* bfrag_ds  = (u16*)alloc((size_t)9 * 4 * 64 * 8 * 2);
  u16* bfrag_out = (u16*)alloc((size_t)8 * 4 * 64 * 8 * 2);

  int* off_f = offs;
  int* off_r = offs + OFFS;
  int* off_c = offs + 2 * OFFS;
  int* el_f = big_el;
  int* el_r = big_el + ETT;
  int* el_c = big_el + 2 * ETT;

  const int* tt_src = e_tt;
  const int* tt_dst = e_tt + ETT;

  const int gT = (NT + 31) / 32;       // 3125
  const int gC = (NC + 31) / 32;       // 782
  const int gM = (NT + 63) / 64;       // 1563 (MFMA blocks)

  // CSR build (bucket-binned counting sort, no global atomics)
  hist_blk_kernel<<<NBLK, 256, 0, stream>>>(tt_src, tt_dst, ect_d, cntblk);
  scan2_blk_kernel<<<NSB, 256, 0, stream>>>(cntblk, scanned, bsum);
  scan2_top_kernel<<<1, 512, 0, stream>>>(bsum, bpre);
  scan2_add_kernel<<<NSB, 256, 0, stream>>>(bpre, scanned);
  bin_kernel<<<NBLK, 256, 0, stream>>>(tt_src, tt_dst, ect_s, ect_d, scanned, bin);
  bucket_fill_kernel<<<3 * NBK, 256, 0, stream>>>(scanned, bin, offs, big_el);

  // weight prep: MFMA frag layouts + fold_cd + cbias (4 blocks)
  prep_kernel<<<4, 256, 0, stream>>>(Wsd, As_sd, Ad_sd, Wds, As_ds, Ad_ds, Wout,
                                     bfrag_sd, bfrag_ds, bfrag_out,
                                     Wcd, Ad_ct, bsd, bds, bct, fold_cd, cbias);

  // node transforms
  pre_t_kernel<<<gT, 256, 0, stream>>>(x_t, Wpt, bpt, fold_cd, ht_bf, aD_ct, NT);
  mfma_logits2_kernel<<<gM, 256, 0, stream>>>((const short*)ht_bf,
      (const short*)bfrag_sd, (const short*)bfrag_ds,
      hs_bf, aS_sd, aD_sd, hd_bf, aS_ds, aD_ds, NT);
  ctx_kernel<<<gC, 256, 0, stream>>>(x_c, Wpc, bpc, Wcs, As_ct, hc_bf, aS_ct, NC);

  // fused gather (sd + ds + ct + cbias + skip + relu) -> x_bf
  gather_all_kernel<<<(NT + 15) / 16, 256, 0, stream>>>(
      off_f, el_f, aS_sd, aD_sd, hs_bf,
      off_r, el_r, aS_ds, aD_ds, hd_bf,
      off_c, el_c, aS_ct, aD_ct, hc_bf,
      ht_bf, cbias, x_bf);

  // final MFMA GEMM -> d_out (fp32)
  mfma_out_kernel<<<gM, 256, 0, stream>>>((const short*)x_bf, (const short*)bfrag_out,
                                          bout, (float*)d_out, NT);
}